// Round 1
// baseline (648.772 us; speedup 1.0000x reference)
//
#include <hip/hip_runtime.h>
#include <hip/hip_bf16.h>

#define T_TOK 4096
#define HID   1024
#define INTER 2048
#define NE    8
#define NE1   9      // 8 routed + 1 shared expert
#define BK    64     // K-tile (bf16 elems); XOR-swizzled chunks, global_load_lds staged
#define MAXT  104    // max 128-row m-tiles: <=71 routed (8192/128+7) + 32 shared
#define NT1   (HID / BK)     // 16 K-steps in GEMM1
#define NT2   (INTER / BK)   // 32 K-steps in GEMM2

typedef __attribute__((ext_vector_type(8))) short short8;
typedef __attribute__((ext_vector_type(8))) unsigned short ushort8v;
typedef __attribute__((ext_vector_type(4))) float f32x4;

__device__ __forceinline__ unsigned short f2bf(float f) {
    __hip_bfloat16 h = __float2bfloat16(f);
    return __builtin_bit_cast(unsigned short, h);
}
__device__ __forceinline__ float bf2f(unsigned short u) {
    unsigned int v = ((unsigned int)u) << 16;
    return __builtin_bit_cast(float, v);
}
__device__ __forceinline__ float sigm(float x) { return 1.0f / (1.0f + __expf(-x)); }

// async global->LDS, 16B per lane. LDS dest = wave-uniform base + lane*16.
__device__ __forceinline__ void async_ld16(const void* g, void* l) {
    __builtin_amdgcn_global_load_lds(
        (const __attribute__((address_space(1))) unsigned int*)g,
        (__attribute__((address_space(3))) unsigned int*)l, 16, 0, 0);
}

// ---------------- generic fp32 -> bf16 cast ----------------
__global__ void cast_kernel(const float* __restrict__ x, unsigned short* __restrict__ xb, int n4) {
    int i = blockIdx.x * blockDim.x + threadIdx.x;
    if (i >= n4) return;
    float4 v = ((const float4*)x)[i];
    ushort4 o;
    o.x = f2bf(v.x); o.y = f2bf(v.y); o.z = f2bf(v.z); o.w = f2bf(v.w);
    ((ushort4*)xb)[i] = o;
}

// ---------- fp32 [K][N] -> bf16 [N][K] transpose+cast, 128k x 64n tiles ----------
__global__ __launch_bounds__(256) void
transpose_cast(const float* __restrict__ W, unsigned short* __restrict__ Wt,
               int K, int N, size_t in_stride_e, size_t out_stride_e) {
    __shared__ float tile[128][65];
    const float* Wb = W + (size_t)blockIdx.z * in_stride_e;
    unsigned short* Wo = Wt + (size_t)blockIdx.z * out_stride_e;
    int n0 = blockIdx.x * 64, k0 = blockIdx.y * 128;
    int tid = threadIdx.x;
    int r = tid >> 4, c = tid & 15;
#pragma unroll
    for (int i = 0; i < 8; i++) {              // read: 128 k-rows x 64 n (256B segs)
        int k = i * 16 + r;
        float4 v = *(const float4*)(Wb + (size_t)(k0 + k) * N + n0 + c * 4);
        tile[k][c * 4 + 0] = v.x; tile[k][c * 4 + 1] = v.y;
        tile[k][c * 4 + 2] = v.z; tile[k][c * 4 + 3] = v.w;
    }
    __syncthreads();
#pragma unroll
    for (int i = 0; i < 4; i++) {              // write: 64 n-rows x 128 k (256B segs)
        int n = i * 16 + r;
        ushort8v o;
#pragma unroll
        for (int j = 0; j < 8; j++) o[j] = f2bf(tile[c * 8 + j][n]);
        *(ushort8v*)(Wo + (size_t)(n0 + n) * K + k0 + c * 8) = o;
    }
}

// ---------------- router: logits + top2 + scatter + inverse map ----------------
__global__ void router_kernel(const float* __restrict__ x, const float* __restrict__ rw,
                              float* __restrict__ logits_out,
                              int* __restrict__ cnt, int* __restrict__ tok_list,
                              float* __restrict__ score_list, int2* __restrict__ inv) {
    int wave = threadIdx.x >> 6;
    int lane = threadIdx.x & 63;
    int t = blockIdx.x * 4 + wave;

    float dot[NE];
#pragma unroll
    for (int e = 0; e < NE; e++) dot[e] = 0.0f;
    const float4* xv = (const float4*)(x + (size_t)t * HID);
    const float4* wv = (const float4*)rw;
#pragma unroll
    for (int j = 0; j < 4; j++) {
        float4 xc = xv[j * 64 + lane];
#pragma unroll
        for (int e = 0; e < NE; e++) {
            float4 wc = wv[e * 256 + j * 64 + lane];
            dot[e] += xc.x * wc.x + xc.y * wc.y + xc.z * wc.z + xc.w * wc.w;
        }
    }
#pragma unroll
    for (int e = 0; e < NE; e++) {
        float v = dot[e];
        for (int m = 1; m < 64; m <<= 1) v += __shfl_xor(v, m, 64);
        dot[e] = v;
    }
    if (lane == 0) {
        float v1 = -1e30f, v2 = -1e30f; int i1 = 0, i2 = 0;
#pragma unroll
        for (int e = 0; e < NE; e++) {
            float v = dot[e];
            logits_out[(size_t)t * NE + e] = v;
            if (v > v1) { v2 = v1; i2 = i1; v1 = v; i1 = e; }
            else if (v > v2) { v2 = v; i2 = e; }
        }
        float s1 = 1.0f / (1.0f + expf(-v1));
        float s2 = 1.0f / (1.0f + expf(-v2));
        int p1 = atomicAdd(&cnt[i1], 1);
        tok_list[i1 * T_TOK + p1] = t; score_list[i1 * T_TOK + p1] = s1;
        int p2 = atomicAdd(&cnt[i2], 1);
        tok_list[i2 * T_TOK + p2] = t; score_list[i2 * T_TOK + p2] = s2;
        inv[t] = make_int2((i1 << 16) | p1, (i2 << 16) | p2);
    }
}

// ---------------- shared-expert list fill (expert 8: all tokens, score 1) ----------------
__global__ void fill_shared_kernel(int* __restrict__ tok_list, float* __restrict__ score_list) {
    int i = blockIdx.x * blockDim.x + threadIdx.x;
    if (i < T_TOK) {
        tok_list[NE * T_TOK + i] = i;
        score_list[NE * T_TOK + i] = 1.0f;
    }
}

// -------- finalize: pad lists, prefix offsets, build dense tile table --------
__global__ void finalize_kernel(const int* __restrict__ cnt, int* __restrict__ offs,
                                int* __restrict__ tiletab,
                                int* __restrict__ tok_list, float* __restrict__ score_list) {
    __shared__ int s_cnt[NE], s_pad[NE];
    if (threadIdx.x == 0) {
        int o = 0, nt = 0;
        for (int e = 0; e < NE1; e++) {
            int c = (e == NE) ? T_TOK : cnt[e];
            int p = (c + 127) & ~127;
            offs[e] = o;
            for (int m = 0; m < (p >> 7); m++) tiletab[nt++] = (e << 8) | m;
            if (e < NE) { s_cnt[e] = c; s_pad[e] = p; }
            o += p;
        }
        for (; nt < MAXT; nt++) tiletab[nt] = -1;
    }
    __syncthreads();
    for (int e = 0; e < NE; e++) {
        for (int i = s_cnt[e] + (int)threadIdx.x; i < s_pad[e]; i += blockDim.x) {
            tok_list[e * T_TOK + i] = 0;
            score_list[e * T_TOK + i] = 0.0f;
        }
    }
}

// ---------------- unified GEMM1: gathered x @ {gate,up}^T, fused score+SwiGLU ----------------
// Double-buffered LDS, counted-vmcnt pipeline: tile t+2 staged while tile t computes,
// tile t+1's loads stay in flight across barriers (never drained to 0 in steady state).
__global__ __launch_bounds__(256) void
moe_g1(const unsigned short* __restrict__ xb, const unsigned short* __restrict__ wg_t,
       const int* __restrict__ tiletab, const int* __restrict__ offs,
       const int* __restrict__ tok_list, const float* __restrict__ score_list,
       unsigned short* __restrict__ h) {
    int tt = tiletab[blockIdx.y];
    if (tt < 0) return;
    int e = tt >> 8, mt = tt & 255;
    int nt = blockIdx.x;  // 0..31, 64 intermediate cols

    __shared__ unsigned short As[2][128 * BK];   // 2 x 16 KB
    __shared__ unsigned short Bg[2][64 * BK];    // 2 x 8 KB
    __shared__ unsigned short Bu[2][64 * BK];    // 2 x 8 KB
    __shared__ int s_tok[128];
    __shared__ float s_sc[128];

    int tid = threadIdx.x, lane = tid & 63;
    int wid = tid >> 6, wm = wid >> 1, wn = wid & 1;

    if (tid < 128) {
        int slot = mt * 128 + tid;
        s_tok[tid] = tok_list[e * T_TOK + slot];
        s_sc[tid] = score_list[e * T_TOK + slot];
    }
    __syncthreads();

    const unsigned short* wg = wg_t + (size_t)e * (4096u * 1024u);
    int rsub = tid >> 3;                       // 0..31 staging row within issue
    int csw = (tid & 7) ^ (rsub & 7);          // XOR-swizzled source chunk
    const unsigned short* pA[4];
#pragma unroll
    for (int i = 0; i < 4; i++)
        pA[i] = xb + (size_t)s_tok[i * 32 + rsub] * HID + csw * 8;
    const unsigned short* pBg[2];
    const unsigned short* pBu[2];
#pragma unroll
    for (int i = 0; i < 2; i++) {
        pBg[i] = wg + (size_t)(nt * 64 + i * 32 + rsub) * HID + csw * 8;
        pBu[i] = wg + (size_t)(INTER + nt * 64 + i * 32 + rsub) * HID + csw * 8;
    }

    // 8 global_load_lds per thread per tile
    auto stage = [&](int buf, int k0) {
        unsigned short* lA = &As[buf][tid * 8];
        unsigned short* lBg = &Bg[buf][tid * 8];
        unsigned short* lBu = &Bu[buf][tid * 8];
#pragma unroll
        for (int i = 0; i < 4; i++) async_ld16(pA[i] + k0, lA + i * 2048);
#pragma unroll
        for (int i = 0; i < 2; i++) {
            async_ld16(pBg[i] + k0, lBg + i * 2048);
            async_ld16(pBu[i] + k0, lBu + i * 2048);
        }
    };

    f32x4 accg[4][2], accu[4][2];
#pragma unroll
    for (int i = 0; i < 4; i++)
#pragma unroll
        for (int j = 0; j < 2; j++) { accg[i][j] = (f32x4)(0.0f); accu[i][j] = (f32x4)(0.0f); }

    int mrow = lane & 15, q = lane >> 4, x7 = lane & 7;

    // pipeline prologue: tiles 0 and 1 in flight; wait tile 0 (8 newest allowed in flight)
    stage(0, 0);
    stage(1, BK);
    asm volatile("s_waitcnt vmcnt(8)" ::: "memory");
    __builtin_amdgcn_s_barrier();

    for (int t = 0; t < NT1; t++) {
        int buf = t & 1;
#pragma unroll
        for (int ksub = 0; ksub < 2; ksub++) {
            int ch = ((ksub * 4 + q) ^ x7) * 8;
            short8 af[4], bg[2], bu[2];
#pragma unroll
            for (int mi = 0; mi < 4; mi++)
                af[mi] = *(const short8*)(&As[buf][(wm * 64 + mi * 16 + mrow) * BK + ch]);
#pragma unroll
            for (int ni = 0; ni < 2; ni++) {
                bg[ni] = *(const short8*)(&Bg[buf][(wn * 32 + ni * 16 + mrow) * BK + ch]);
                bu[ni] = *(const short8*)(&Bu[buf][(wn * 32 + ni * 16 + mrow) * BK + ch]);
            }
#pragma unroll
            for (int mi = 0; mi < 4; mi++)
#pragma unroll
                for (int ni = 0; ni < 2; ni++) {
                    accg[mi][ni] = __builtin_amdgcn_mfma_f32_16x16x32_bf16(af[mi], bg[ni], accg[mi][ni], 0, 0, 0);
                    accu[mi][ni] = __builtin_amdgcn_mfma_f32_16x16x32_bf16(af[mi], bu[ni], accu[mi][ni], 0, 0, 0);
                }
        }
        // all this wave's ds_reads of buf complete before signaling arrival
        asm volatile("s_waitcnt lgkmcnt(0)" ::: "memory");
        __builtin_amdgcn_s_barrier();              // B1: everyone done READING buf
        if (t + 2 < NT1) {
            stage(buf, (t + 2) * BK);              // overwrite freed buf with tile t+2
            asm volatile("s_waitcnt vmcnt(8)" ::: "memory");  // tile t+1 landed; t+2 flies
        } else {
            asm volatile("s_waitcnt vmcnt(0)" ::: "memory");  // tail: drain remaining
        }
        __builtin_amdgcn_s_barrier();              // B2: tile t+1 visible to all waves
    }

    size_t rowbase = (size_t)offs[e] + (size_t)mt * 128;
    int ibase = nt * 64 + wn * 32;
#pragma unroll
    for (int mi = 0; mi < 4; mi++)
#pragma unroll
        for (int ni = 0; ni < 2; ni++)
#pragma unroll
            for (int r = 0; r < 4; r++) {
                int m = wm * 64 + mi * 16 + (lane >> 4) * 4 + r;
                int i = ibase + ni * 16 + (lane & 15);
                float s = s_sc[m];
                float g = accg[mi][ni][r] * s;
                float u = accu[mi][ni][r] * s;
                h[(rowbase + m) * INTER + i] = f2bf(u * g * sigm(g));
            }
}

// ---------------- unified GEMM2: h @ down^T -> dense r_out (no atomics) ----------------
__global__ __launch_bounds__(256) void
moe_g2(const unsigned short* __restrict__ h, const unsigned short* __restrict__ wd_t,
       const int* __restrict__ tiletab, const int* __restrict__ offs,
       unsigned short* __restrict__ r_out) {
    int tt = tiletab[blockIdx.y];
    if (tt < 0) return;
    int e = tt >> 8, mt = tt & 255;
    int nt = blockIdx.x;  // 0..7, 128 H-cols

    __shared__ unsigned short As[2][128 * BK];   // 2 x 16 KB
    __shared__ unsigned short Bs[2][128 * BK];   // 2 x 16 KB

    int tid = threadIdx.x, lane = tid & 63;
    int wid = tid >> 6, wm = wid >> 1, wn = wid & 1;
    size_t rowbase = (size_t)offs[e] + (size_t)mt * 128;

    const unsigned short* wd = wd_t + (size_t)e * (1024u * 2048u);
    int rsub = tid >> 3;
    int csw = (tid & 7) ^ (rsub & 7);
    const unsigned short* pA[4];
    const unsigned short* pB[4];
#pragma unroll
    for (int i = 0; i < 4; i++) {
        pA[i] = h + (rowbase + i * 32 + rsub) * INTER + csw * 8;
        pB[i] = wd + (size_t)(nt * 128 + i * 32 + rsub) * INTER + csw * 8;
    }

    auto stage = [&](int buf, int k0) {
        unsigned short* lA = &As[buf][tid * 8];
        unsigned short* lB = &Bs[buf][tid * 8];
#pragma unroll
        for (int i = 0; i < 4; i++) {
            async_ld16(pA[i] + k0, lA + i * 2048);
            async_ld16(pB[i] + k0, lB + i * 2048);
        }
    };

    f32x4 acc[4][4];
#pragma unroll
    for (int i = 0; i < 4; i++)
#pragma unroll
        for (int j = 0; j < 4; j++) acc[i][j] = (f32x4)(0.0f);

    int mrow = lane & 15, q = lane >> 4, x7 = lane & 7;

    stage(0, 0);
    stage(1, BK);
    asm volatile("s_waitcnt vmcnt(8)" ::: "memory");
    __builtin_amdgcn_s_barrier();

    for (int t = 0; t < NT2; t++) {
        int buf = t & 1;
#pragma unroll
        for (int ksub = 0; ksub < 2; ksub++) {
            int ch = ((ksub * 4 + q) ^ x7) * 8;
            short8 af[4], bf_[4];
#pragma unroll
            for (int mi = 0; mi < 4; mi++)
                af[mi] = *(const short8*)(&As[buf][(wm * 64 + mi * 16 + mrow) * BK + ch]);
#pragma unroll
            for (int ni = 0; ni < 4; ni++)
                bf_[ni] = *(const short8*)(&Bs[buf][(wn * 64 + ni * 16 + mrow) * BK + ch]);
#pragma unroll
            for (int mi = 0; mi < 4; mi++)
#pragma unroll
                for (int ni = 0; ni < 4; ni++)
                    acc[mi][ni] = __builtin_amdgcn_mfma_f32_16x16x32_bf16(af[mi], bf_[ni], acc[mi][ni], 0, 0, 0);
        }
        asm volatile("s_waitcnt lgkmcnt(0)" ::: "memory");
        __builtin_amdgcn_s_barrier();              // B1
        if (t + 2 < NT2) {
            stage(buf, (t + 2) * BK);
            asm volatile("s_waitcnt vmcnt(8)" ::: "memory");
        } else {
            asm volatile("s_waitcnt vmcnt(0)" ::: "memory");
        }
        __builtin_amdgcn_s_barrier();              // B2
    }

#pragma unroll
    for (int mi = 0; mi < 4; mi++)
#pragma unroll
        for (int ni = 0; ni < 4; ni++)
#pragma unroll
            for (int r = 0; r < 4; r++) {
                int m = wm * 64 + mi * 16 + (lane >> 4) * 4 + r;
                int n = nt * 128 + wn * 64 + ni * 16 + (lane & 15);
                r_out[(rowbase + m) * HID + n] = f2bf(acc[mi][ni][r]);
            }
}

// ---------------- combine: out[t] = shared + two routed contributions ----------------
__global__ void combine_kernel(const unsigned short* __restrict__ r_out,
                               const int2* __restrict__ inv, const int* __restrict__ offs,
                               float* __restrict__ out) {
    int t = blockIdx.x, tid = threadIdx.x;
    int2 iv = inv[t];
    size_t r1 = (size_t)(offs[iv.x >> 16] + (iv.x & 0xffff)) * HID;
    size_t r2 = (size_t)(offs[iv.y >> 16] + (iv.y & 0xffff)) * HID;
    size_t rs = (size_t)(offs[NE] + t) * HID;
    int i = tid * 4;
    ushort4 a = *(const ushort4*)(r_out + r1 + i);
    ushort4 b = *(const ushort4*)(r_out + r2 + i);
    ushort4 c = *(const ushort4*)(r_out + rs + i);
    float4 o;
    o.x = bf2f(a.x) + bf2f(b.x) + bf2f(c.x);
    o.y = bf2f(a.y) + bf2f(b.y) + bf2f(c.y);
    o.z = bf2f(a.z) + bf2f(b.z) + bf2f(c.z);
    o.w = bf2f(a.w) + bf2f(b.w) + bf2f(c.w);
    *(float4*)(out + (size_t)t * HID + i) = o;
}

extern "C" void kernel_launch(void* const* d_in, const int* in_sizes, int n_in,
                              void* d_out, int out_size, void* d_ws, size_t ws_size,
                              hipStream_t stream) {
    const float* x   = (const float*)d_in[0];
    const float* rw  = (const float*)d_in[1];
    const float* gup = (const float*)d_in[2];
    const float* dwn = (const float*)d_in[3];
    const float* sgw = (const float*)d_in[4];
    const float* suw = (const float*)d_in[5];
    const float* sdw = (const float*)d_in[6];
    float* out = (float*)d_out;
    float* logits = out + (size_t)T_TOK * HID;

    char* ws = (char*)d_ws;
    int*   cnt        = (int*)(ws + 0);
    int*   offs       = (int*)(ws + 64);
    int*   tiletab    = (int*)(ws + 128);                   // 104 ints
    int2*  inv        = (int2*)(ws + 4096);                 // 32 KB
    int*   tok_list   = (int*)(ws + 65536);                 // 144 KB
    float* score_list = (float*)(ws + 212992);              // 144 KB
    unsigned short* xb      = (unsigned short*)(ws + 524288);        // 8 MB
    unsigned short* w_gup_t = (unsigned short*)(ws + 9437184);       // 72 MB
    unsigned short* w_dwn_t = (unsigned short*)(ws + 89128960);      // 36 MB
    unsigned short* h       = (unsigned short*)(ws + 134217728);     // 52 MB
    unsigned short* r_out   = (unsigned short*)(ws + 201326592);     // 26 MB

    hipMemsetAsync(cnt, 0, NE * sizeof(int), stream);

    // weight prep: transpose routed weights to bf16 [N][K]; shared already [N][K]
    {
        dim3 g(4096 / 64, 1024 / 128, NE);
        transpose_cast<<<g, 256, 0, stream>>>(gup, w_gup_t, 1024, 4096,
                                              (size_t)1024 * 4096, (size_t)4096 * 1024);
    }
    {
        dim3 g(1024 / 64, 2048 / 128, NE);
        transpose_cast<<<g, 256, 0, stream>>>(dwn, w_dwn_t, 2048, 1024,
                                              (size_t)2048 * 1024, (size_t)1024 * 2048);
    }
    unsigned short* wg8 = w_gup_t + (size_t)NE * 4096 * 1024;
    cast_kernel<<<(2048 * 1024 / 4 + 255) / 256, 256, 0, stream>>>(sgw, wg8, 2048 * 1024 / 4);
    cast_kernel<<<(2048 * 1024 / 4 + 255) / 256, 256, 0, stream>>>(suw, wg8 + 2048 * 1024, 2048 * 1024 / 4);
    cast_kernel<<<(1024 * 2048 / 4 + 255) / 256, 256, 0, stream>>>(sdw, w_dwn_t + (size_t)NE * 1024 * 2048, 1024 * 2048 / 4);
    cast_kernel<<<(T_TOK * HID / 4 + 255) / 256, 256, 0, stream>>>(x, xb, T_TOK * HID / 4);

    router_kernel<<<T_TOK / 4, 256, 0, stream>>>(x, rw, logits, cnt, tok_list, score_list, inv);
    fill_shared_kernel<<<T_TOK / 256, 256, 0, stream>>>(tok_list, score_list);
    finalize_kernel<<<1, 128, 0, stream>>>(cnt, offs, tiletab, tok_list, score_list);

    dim3 g1(INTER / 64, MAXT);
    moe_g1<<<g1, 256, 0, stream>>>(xb, w_gup_t, tiletab, offs, tok_list, score_list, h);
    dim3 g2(HID / 128, MAXT);
    moe_g2<<<g2, 256, 0, stream>>>(h, w_dwn_t, tiletab, offs, r_out);
    combine_kernel<<<T_TOK, 256, 0, stream>>>(r_out, inv, offs, out);
}

// Round 2
// 614.251 us; speedup vs baseline: 1.0562x; 1.0562x over previous
//
#include <hip/hip_runtime.h>
#include <hip/hip_bf16.h>

#define T_TOK 4096
#define HID   1024
#define INTER 2048
#define NE    8
#define NE1   9      // 8 routed + 1 shared expert
#define BK    64     // K-tile (bf16 elems); XOR-swizzled chunks, global_load_lds staged
#define MAXT  104    // max 128-row m-tiles: <=71 routed (8192/128+7) + 32 shared

typedef __attribute__((ext_vector_type(8))) short short8;
typedef __attribute__((ext_vector_type(8))) unsigned short ushort8v;
typedef __attribute__((ext_vector_type(4))) float f32x4;

__device__ __forceinline__ unsigned short f2bf(float f) {
    __hip_bfloat16 h = __float2bfloat16(f);
    return __builtin_bit_cast(unsigned short, h);
}
__device__ __forceinline__ float bf2f(unsigned short u) {
    unsigned int v = ((unsigned int)u) << 16;
    return __builtin_bit_cast(float, v);
}
__device__ __forceinline__ float sigm(float x) { return 1.0f / (1.0f + __expf(-x)); }

// async global->LDS, 16B per lane. LDS dest = wave-uniform base + lane*16.
__device__ __forceinline__ void async_ld16(const void* g, void* l) {
    __builtin_amdgcn_global_load_lds(
        (const __attribute__((address_space(1))) unsigned int*)g,
        (__attribute__((address_space(3))) unsigned int*)l, 16, 0, 0);
}

// ---------------- generic fp32 -> bf16 cast ----------------
__global__ void cast_kernel(const float* __restrict__ x, unsigned short* __restrict__ xb, int n4) {
    int i = blockIdx.x * blockDim.x + threadIdx.x;
    if (i >= n4) return;
    float4 v = ((const float4*)x)[i];
    ushort4 o;
    o.x = f2bf(v.x); o.y = f2bf(v.y); o.z = f2bf(v.z); o.w = f2bf(v.w);
    ((ushort4*)xb)[i] = o;
}

// ---------- fp32 [K][N] -> bf16 [N][K] transpose+cast, 128k x 64n tiles ----------
__global__ __launch_bounds__(256) void
transpose_cast(const float* __restrict__ W, unsigned short* __restrict__ Wt,
               int K, int N, size_t in_stride_e, size_t out_stride_e) {
    __shared__ float tile[128][65];
    const float* Wb = W + (size_t)blockIdx.z * in_stride_e;
    unsigned short* Wo = Wt + (size_t)blockIdx.z * out_stride_e;
    int n0 = blockIdx.x * 64, k0 = blockIdx.y * 128;
    int tid = threadIdx.x;
    int r = tid >> 4, c = tid & 15;
#pragma unroll
    for (int i = 0; i < 8; i++) {              // read: 128 k-rows x 64 n (256B segs)
        int k = i * 16 + r;
        float4 v = *(const float4*)(Wb + (size_t)(k0 + k) * N + n0 + c * 4);
        tile[k][c * 4 + 0] = v.x; tile[k][c * 4 + 1] = v.y;
        tile[k][c * 4 + 2] = v.z; tile[k][c * 4 + 3] = v.w;
    }
    __syncthreads();
#pragma unroll
    for (int i = 0; i < 4; i++) {              // write: 64 n-rows x 128 k (256B segs)
        int n = i * 16 + r;
        ushort8v o;
#pragma unroll
        for (int j = 0; j < 8; j++) o[j] = f2bf(tile[c * 8 + j][n]);
        *(ushort8v*)(Wo + (size_t)(n0 + n) * K + k0 + c * 8) = o;
    }
}

// ---------------- router: logits + top2 + scatter + inverse map ----------------
__global__ void router_kernel(const float* __restrict__ x, const float* __restrict__ rw,
                              float* __restrict__ logits_out,
                              int* __restrict__ cnt, int* __restrict__ tok_list,
                              float* __restrict__ score_list, int2* __restrict__ inv) {
    int wave = threadIdx.x >> 6;
    int lane = threadIdx.x & 63;
    int t = blockIdx.x * 4 + wave;

    float dot[NE];
#pragma unroll
    for (int e = 0; e < NE; e++) dot[e] = 0.0f;
    const float4* xv = (const float4*)(x + (size_t)t * HID);
    const float4* wv = (const float4*)rw;
#pragma unroll
    for (int j = 0; j < 4; j++) {
        float4 xc = xv[j * 64 + lane];
#pragma unroll
        for (int e = 0; e < NE; e++) {
            float4 wc = wv[e * 256 + j * 64 + lane];
            dot[e] += xc.x * wc.x + xc.y * wc.y + xc.z * wc.z + xc.w * wc.w;
        }
    }
#pragma unroll
    for (int e = 0; e < NE; e++) {
        float v = dot[e];
        for (int m = 1; m < 64; m <<= 1) v += __shfl_xor(v, m, 64);
        dot[e] = v;
    }
    if (lane == 0) {
        float v1 = -1e30f, v2 = -1e30f; int i1 = 0, i2 = 0;
#pragma unroll
        for (int e = 0; e < NE; e++) {
            float v = dot[e];
            logits_out[(size_t)t * NE + e] = v;
            if (v > v1) { v2 = v1; i2 = i1; v1 = v; i1 = e; }
            else if (v > v2) { v2 = v; i2 = e; }
        }
        float s1 = 1.0f / (1.0f + expf(-v1));
        float s2 = 1.0f / (1.0f + expf(-v2));
        int p1 = atomicAdd(&cnt[i1], 1);
        tok_list[i1 * T_TOK + p1] = t; score_list[i1 * T_TOK + p1] = s1;
        int p2 = atomicAdd(&cnt[i2], 1);
        tok_list[i2 * T_TOK + p2] = t; score_list[i2 * T_TOK + p2] = s2;
        inv[t] = make_int2((i1 << 16) | p1, (i2 << 16) | p2);
    }
}

// ---------------- shared-expert list fill (expert 8: all tokens, score 1) ----------------
__global__ void fill_shared_kernel(int* __restrict__ tok_list, float* __restrict__ score_list) {
    int i = blockIdx.x * blockDim.x + threadIdx.x;
    if (i < T_TOK) {
        tok_list[NE * T_TOK + i] = i;
        score_list[NE * T_TOK + i] = 1.0f;
    }
}

// -------- finalize: pad lists, prefix offsets, build dense tile table --------
__global__ void finalize_kernel(const int* __restrict__ cnt, int* __restrict__ offs,
                                int* __restrict__ tiletab,
                                int* __restrict__ tok_list, float* __restrict__ score_list) {
    __shared__ int s_cnt[NE], s_pad[NE];
    if (threadIdx.x == 0) {
        int o = 0, nt = 0;
        for (int e = 0; e < NE1; e++) {
            int c = (e == NE) ? T_TOK : cnt[e];
            int p = (c + 127) & ~127;
            offs[e] = o;
            for (int m = 0; m < (p >> 7); m++) tiletab[nt++] = (e << 8) | m;
            if (e < NE) { s_cnt[e] = c; s_pad[e] = p; }
            o += p;
        }
        for (; nt < MAXT; nt++) tiletab[nt] = -1;
    }
    __syncthreads();
    for (int e = 0; e < NE; e++) {
        for (int i = s_cnt[e] + (int)threadIdx.x; i < s_pad[e]; i += blockDim.x) {
            tok_list[e * T_TOK + i] = 0;
            score_list[e * T_TOK + i] = 0.0f;
        }
    }
}

// ---------------- unified GEMM1: gathered x @ {gate,up}^T, fused score+SwiGLU ----------------
// Wide tile: 128 rows x 128 i-cols (gate+up) per block; 64 MFMA per barrier per wave.
__global__ __launch_bounds__(256, 2) void
moe_g1(const unsigned short* __restrict__ xb, const unsigned short* __restrict__ wg_t,
       const int* __restrict__ tiletab, const int* __restrict__ offs,
       const int* __restrict__ tok_list, const float* __restrict__ score_list,
       unsigned short* __restrict__ h) {
    int tt = tiletab[blockIdx.y];
    if (tt < 0) return;
    int e = tt >> 8, mt = tt & 255;
    int nt = blockIdx.x;  // 0..15, 128 intermediate cols

    __shared__ unsigned short As[128 * BK];   // 16 KB
    __shared__ unsigned short Bg[128 * BK];   // 16 KB
    __shared__ unsigned short Bu[128 * BK];   // 16 KB
    __shared__ int s_tok[128];
    __shared__ float s_sc[128];

    int tid = threadIdx.x, lane = tid & 63;
    int wid = tid >> 6, wm = wid >> 1, wn = wid & 1;

    if (tid < 128) {
        int slot = mt * 128 + tid;
        s_tok[tid] = tok_list[e * T_TOK + slot];
        s_sc[tid] = score_list[e * T_TOK + slot];
    }
    __syncthreads();

    const unsigned short* wg = wg_t + (size_t)e * (4096u * 1024u);
    int rsub = tid >> 3;                       // 0..31 staging row within issue
    int csw = (tid & 7) ^ (rsub & 7);          // XOR-swizzled source chunk
    const unsigned short* pA[4];
#pragma unroll
    for (int i = 0; i < 4; i++)
        pA[i] = xb + (size_t)s_tok[i * 32 + rsub] * HID + csw * 8;
    const unsigned short* pBg[4];
    const unsigned short* pBu[4];
#pragma unroll
    for (int i = 0; i < 4; i++) {
        pBg[i] = wg + (size_t)(nt * 128 + i * 32 + rsub) * HID + csw * 8;
        pBu[i] = wg + (size_t)(INTER + nt * 128 + i * 32 + rsub) * HID + csw * 8;
    }
    unsigned short* lA = As + tid * 8;         // + i*2048 per issue
    unsigned short* lBg = Bg + tid * 8;
    unsigned short* lBu = Bu + tid * 8;

    f32x4 accg[4][4], accu[4][4];
#pragma unroll
    for (int i = 0; i < 4; i++)
#pragma unroll
        for (int j = 0; j < 4; j++) { accg[i][j] = (f32x4)(0.0f); accu[i][j] = (f32x4)(0.0f); }

    int mrow = lane & 15, q = lane >> 4, x7 = lane & 7;
    for (int k0 = 0; k0 < HID; k0 += BK) {
#pragma unroll
        for (int i = 0; i < 4; i++) {
            async_ld16(pA[i] + k0, lA + i * 2048);
            async_ld16(pBg[i] + k0, lBg + i * 2048);
            async_ld16(pBu[i] + k0, lBu + i * 2048);
        }
        __syncthreads();
#pragma unroll
        for (int ksub = 0; ksub < 2; ksub++) {
            int ch = ((ksub * 4 + q) ^ x7) * 8;
            short8 af[4], bg[4], bu[4];
#pragma unroll
            for (int mi = 0; mi < 4; mi++)
                af[mi] = *(const short8*)(As + (wm * 64 + mi * 16 + mrow) * BK + ch);
#pragma unroll
            for (int ni = 0; ni < 4; ni++) {
                bg[ni] = *(const short8*)(Bg + (wn * 64 + ni * 16 + mrow) * BK + ch);
                bu[ni] = *(const short8*)(Bu + (wn * 64 + ni * 16 + mrow) * BK + ch);
            }
#pragma unroll
            for (int mi = 0; mi < 4; mi++)
#pragma unroll
                for (int ni = 0; ni < 4; ni++) {
                    accg[mi][ni] = __builtin_amdgcn_mfma_f32_16x16x32_bf16(af[mi], bg[ni], accg[mi][ni], 0, 0, 0);
                    accu[mi][ni] = __builtin_amdgcn_mfma_f32_16x16x32_bf16(af[mi], bu[ni], accu[mi][ni], 0, 0, 0);
                }
        }
        __syncthreads();
    }
    size_t rowbase = (size_t)offs[e] + (size_t)mt * 128;
    int ibase = nt * 128 + wn * 64;
#pragma unroll
    for (int mi = 0; mi < 4; mi++)
#pragma unroll
        for (int ni = 0; ni < 4; ni++)
#pragma unroll
            for (int r = 0; r < 4; r++) {
                int m = wm * 64 + mi * 16 + q * 4 + r;
                int i = ibase + ni * 16 + mrow;
                float s = s_sc[m];
                float g = accg[mi][ni][r] * s;
                float u = accu[mi][ni][r] * s;
                h[(rowbase + m) * INTER + i] = f2bf(u * g * sigm(g));
            }
}

// ---------------- unified GEMM2: h @ down^T -> dense r_out (no atomics) ----------------
__global__ __launch_bounds__(256) void
moe_g2(const unsigned short* __restrict__ h, const unsigned short* __restrict__ wd_t,
       const int* __restrict__ tiletab, const int* __restrict__ offs,
       unsigned short* __restrict__ r_out) {
    int tt = tiletab[blockIdx.y];
    if (tt < 0) return;
    int e = tt >> 8, mt = tt & 255;
    int nt = blockIdx.x;  // 0..7, 128 H-cols

    __shared__ unsigned short As[128 * BK];   // 16 KB
    __shared__ unsigned short Bs[128 * BK];   // 16 KB

    int tid = threadIdx.x, lane = tid & 63;
    int wid = tid >> 6, wm = wid >> 1, wn = wid & 1;
    size_t rowbase = (size_t)offs[e] + (size_t)mt * 128;

    const unsigned short* wd = wd_t + (size_t)e * (1024u * 2048u);
    int rsub = tid >> 3;
    int csw = (tid & 7) ^ (rsub & 7);
    const unsigned short* pA[4];
    const unsigned short* pB[4];
#pragma unroll
    for (int i = 0; i < 4; i++) {
        pA[i] = h + (rowbase + i * 32 + rsub) * INTER + csw * 8;
        pB[i] = wd + (size_t)(nt * 128 + i * 32 + rsub) * INTER + csw * 8;
    }
    unsigned short* lA = As + tid * 8;
    unsigned short* lB = Bs + tid * 8;

    f32x4 acc[4][4];
#pragma unroll
    for (int i = 0; i < 4; i++)
#pragma unroll
        for (int j = 0; j < 4; j++) acc[i][j] = (f32x4)(0.0f);

    int mrow = lane & 15, q = lane >> 4, x7 = lane & 7;
    for (int k0 = 0; k0 < INTER; k0 += BK) {
#pragma unroll
        for (int i = 0; i < 4; i++) {
            async_ld16(pA[i] + k0, lA + i * 2048);
            async_ld16(pB[i] + k0, lB + i * 2048);
        }
        __syncthreads();
#pragma unroll
        for (int ksub = 0; ksub < 2; ksub++) {
            int ch = ((ksub * 4 + q) ^ x7) * 8;
            short8 af[4], bf_[4];
#pragma unroll
            for (int mi = 0; mi < 4; mi++)
                af[mi] = *(const short8*)(As + (wm * 64 + mi * 16 + mrow) * BK + ch);
#pragma unroll
            for (int ni = 0; ni < 4; ni++)
                bf_[ni] = *(const short8*)(Bs + (wn * 64 + ni * 16 + mrow) * BK + ch);
#pragma unroll
            for (int mi = 0; mi < 4; mi++)
#pragma unroll
                for (int ni = 0; ni < 4; ni++)
                    acc[mi][ni] = __builtin_amdgcn_mfma_f32_16x16x32_bf16(af[mi], bf_[ni], acc[mi][ni], 0, 0, 0);
        }
        __syncthreads();
    }
#pragma unroll
    for (int mi = 0; mi < 4; mi++)
#pragma unroll
        for (int ni = 0; ni < 4; ni++)
#pragma unroll
            for (int r = 0; r < 4; r++) {
                int m = wm * 64 + mi * 16 + (lane >> 4) * 4 + r;
                int n = nt * 128 + wn * 64 + ni * 16 + (lane & 15);
                r_out[(rowbase + m) * HID + n] = f2bf(acc[mi][ni][r]);
            }
}

// ---------------- combine: out[t] = shared + two routed contributions ----------------
__global__ void combine_kernel(const unsigned short* __restrict__ r_out,
                               const int2* __restrict__ inv, const int* __restrict__ offs,
                               float* __restrict__ out) {
    int t = blockIdx.x, tid = threadIdx.x;
    int2 iv = inv[t];
    size_t r1 = (size_t)(offs[iv.x >> 16] + (iv.x & 0xffff)) * HID;
    size_t r2 = (size_t)(offs[iv.y >> 16] + (iv.y & 0xffff)) * HID;
    size_t rs = (size_t)(offs[NE] + t) * HID;
    int i = tid * 4;
    ushort4 a = *(const ushort4*)(r_out + r1 + i);
    ushort4 b = *(const ushort4*)(r_out + r2 + i);
    ushort4 c = *(const ushort4*)(r_out + rs + i);
    float4 o;
    o.x = bf2f(a.x) + bf2f(b.x) + bf2f(c.x);
    o.y = bf2f(a.y) + bf2f(b.y) + bf2f(c.y);
    o.z = bf2f(a.z) + bf2f(b.z) + bf2f(c.z);
    o.w = bf2f(a.w) + bf2f(b.w) + bf2f(c.w);
    *(float4*)(out + (size_t)t * HID + i) = o;
}

extern "C" void kernel_launch(void* const* d_in, const int* in_sizes, int n_in,
                              void* d_out, int out_size, void* d_ws, size_t ws_size,
                              hipStream_t stream) {
    const float* x   = (const float*)d_in[0];
    const float* rw  = (const float*)d_in[1];
    const float* gup = (const float*)d_in[2];
    const float* dwn = (const float*)d_in[3];
    const float* sgw = (const float*)d_in[4];
    const float* suw = (const float*)d_in[5];
    const float* sdw = (const float*)d_in[6];
    float* out = (float*)d_out;
    float* logits = out + (size_t)T_TOK * HID;

    char* ws = (char*)d_ws;
    int*   cnt        = (int*)(ws + 0);
    int*   offs       = (int*)(ws + 64);
    int*   tiletab    = (int*)(ws + 128);                   // 104 ints
    int2*  inv        = (int2*)(ws + 4096);                 // 32 KB
    int*   tok_list   = (int*)(ws + 65536);                 // 144 KB
    float* score_list = (float*)(ws + 212992);              // 144 KB
    unsigned short* xb      = (unsigned short*)(ws + 524288);        // 8 MB
    unsigned short* w_gup_t = (unsigned short*)(ws + 9437184);       // 72 MB
    unsigned short* w_dwn_t = (unsigned short*)(ws + 89128960);      // 36 MB
    unsigned short* h       = (unsigned short*)(ws + 134217728);     // 52 MB
    unsigned short* r_out   = (unsigned short*)(ws + 201326592);     // 26 MB

    hipMemsetAsync(cnt, 0, NE * sizeof(int), stream);

    // weight prep: transpose routed weights to bf16 [N][K]; shared already [N][K]
    {
        dim3 g(4096 / 64, 1024 / 128, NE);
        transpose_cast<<<g, 256, 0, stream>>>(gup, w_gup_t, 1024, 4096,
                                              (size_t)1024 * 4096, (size_t)4096 * 1024);
    }
    {
        dim3 g(1024 / 64, 2048 / 128, NE);
        transpose_cast<<<g, 256, 0, stream>>>(dwn, w_dwn_t, 2048, 1024,
                                              (size_t)2048 * 1024, (size_t)1024 * 2048);
    }
    unsigned short* wg8 = w_gup_t + (size_t)NE * 4096 * 1024;
    cast_kernel<<<(2048 * 1024 / 4 + 255) / 256, 256, 0, stream>>>(sgw, wg8, 2048 * 1024 / 4);
    cast_kernel<<<(2048 * 1024 / 4 + 255) / 256, 256, 0, stream>>>(suw, wg8 + 2048 * 1024, 2048 * 1024 / 4);
    cast_kernel<<<(1024 * 2048 / 4 + 255) / 256, 256, 0, stream>>>(sdw, w_dwn_t + (size_t)NE * 1024 * 2048, 1024 * 2048 / 4);
    cast_kernel<<<(T_TOK * HID / 4 + 255) / 256, 256, 0, stream>>>(x, xb, T_TOK * HID / 4);

    router_kernel<<<T_TOK / 4, 256, 0, stream>>>(x, rw, logits, cnt, tok_list, score_list, inv);
    fill_shared_kernel<<<T_TOK / 256, 256, 0, stream>>>(tok_list, score_list);
    finalize_kernel<<<1, 128, 0, stream>>>(cnt, offs, tiletab, tok_list, score_list);

    dim3 g1(INTER / 128, MAXT);
    moe_g1<<<g1, 256, 0, stream>>>(xb, w_gup_t, tiletab, offs, tok_list, score_list, h);
    dim3 g2(HID / 128, MAXT);
    moe_g2<<<g2, 256, 0, stream>>>(h, w_dwn_t, tiletab, offs, r_out);
    combine_kernel<<<T_TOK, 256, 0, stream>>>(r_out, inv, offs, out);
}

// Round 3
// 604.502 us; speedup vs baseline: 1.0732x; 1.0161x over previous
//
#include <hip/hip_runtime.h>
#include <hip/hip_bf16.h>

#define T_TOK 4096
#define HID   1024
#define INTER 2048
#define NE    8
#define NE1   9      // 8 routed + 1 shared expert
#define BK    64     // K-tile (bf16 elems); XOR-swizzled chunks, global_load_lds staged
#define MAXT  104    // max 128-row m-tiles: <=71 routed (8192/128+7) + 32 shared

typedef __attribute__((ext_vector_type(8))) short short8;
typedef __attribute__((ext_vector_type(8))) unsigned short ushort8v;
typedef __attribute__((ext_vector_type(4))) float f32x4;

__device__ __forceinline__ unsigned short f2bf(float f) {
    __hip_bfloat16 h = __float2bfloat16(f);
    return __builtin_bit_cast(unsigned short, h);
}
__device__ __forceinline__ float bf2f(unsigned short u) {
    unsigned int v = ((unsigned int)u) << 16;
    return __builtin_bit_cast(float, v);
}
__device__ __forceinline__ float sigm(float x) { return 1.0f / (1.0f + __expf(-x)); }

// async global->LDS, 16B per lane. LDS dest = wave-uniform base + lane*16.
__device__ __forceinline__ void async_ld16(const void* g, void* l) {
    __builtin_amdgcn_global_load_lds(
        (const __attribute__((address_space(1))) unsigned int*)g,
        (__attribute__((address_space(3))) unsigned int*)l, 16, 0, 0);
}

// ---------------- fused fp32 -> bf16 cast for the 3 shared-expert weights ----------------
__global__ void cast3_kernel(const float* __restrict__ a, const float* __restrict__ b,
                             const float* __restrict__ c,
                             unsigned short* __restrict__ da, unsigned short* __restrict__ db,
                             unsigned short* __restrict__ dc, int n4each) {
    int i = blockIdx.x * blockDim.x + threadIdx.x;
    int region = i / n4each;              // uniform per block (n4each % 256 == 0)
    int local = i - region * n4each;
    const float* src = (region == 0) ? a : (region == 1) ? b : c;
    unsigned short* dst = (region == 0) ? da : (region == 1) ? db : dc;
    float4 v = ((const float4*)src)[local];
    ushort4 o;
    o.x = f2bf(v.x); o.y = f2bf(v.y); o.z = f2bf(v.z); o.w = f2bf(v.w);
    ((ushort4*)dst)[local] = o;
}

// ---------- fp32 [K][N] -> bf16 [N][K] transpose+cast, 128k x 64n tiles ----------
__global__ __launch_bounds__(256) void
transpose_cast(const float* __restrict__ W, unsigned short* __restrict__ Wt,
               int K, int N, size_t in_stride_e, size_t out_stride_e) {
    __shared__ float tile[128][65];
    const float* Wb = W + (size_t)blockIdx.z * in_stride_e;
    unsigned short* Wo = Wt + (size_t)blockIdx.z * out_stride_e;
    int n0 = blockIdx.x * 64, k0 = blockIdx.y * 128;
    int tid = threadIdx.x;
    int r = tid >> 4, c = tid & 15;
#pragma unroll
    for (int i = 0; i < 8; i++) {              // read: 128 k-rows x 64 n (256B segs)
        int k = i * 16 + r;
        float4 v = *(const float4*)(Wb + (size_t)(k0 + k) * N + n0 + c * 4);
        tile[k][c * 4 + 0] = v.x; tile[k][c * 4 + 1] = v.y;
        tile[k][c * 4 + 2] = v.z; tile[k][c * 4 + 3] = v.w;
    }
    __syncthreads();
#pragma unroll
    for (int i = 0; i < 4; i++) {              // write: 64 n-rows x 128 k (256B segs)
        int n = i * 16 + r;
        ushort8v o;
#pragma unroll
        for (int j = 0; j < 8; j++) o[j] = f2bf(tile[c * 8 + j][n]);
        *(ushort8v*)(Wo + (size_t)(n0 + n) * K + k0 + c * 8) = o;
    }
}

// ------- router: logits + top2 + scatter + inverse map + fused x->bf16 cast -------
__global__ void router_kernel(const float* __restrict__ x, const float* __restrict__ rw,
                              float* __restrict__ logits_out,
                              int* __restrict__ cnt, int* __restrict__ tok_list,
                              float* __restrict__ score_list, int2* __restrict__ inv,
                              unsigned short* __restrict__ xb) {
    int wave = threadIdx.x >> 6;
    int lane = threadIdx.x & 63;
    int t = blockIdx.x * 4 + wave;

    float dot[NE];
#pragma unroll
    for (int e = 0; e < NE; e++) dot[e] = 0.0f;
    const float4* xv = (const float4*)(x + (size_t)t * HID);
    ushort4* xo = (ushort4*)(xb + (size_t)t * HID);
    const float4* wv = (const float4*)rw;
#pragma unroll
    for (int j = 0; j < 4; j++) {
        float4 xc = xv[j * 64 + lane];
        ushort4 o;
        o.x = f2bf(xc.x); o.y = f2bf(xc.y); o.z = f2bf(xc.z); o.w = f2bf(xc.w);
        xo[j * 64 + lane] = o;                 // fused bf16 cast of x
#pragma unroll
        for (int e = 0; e < NE; e++) {
            float4 wc = wv[e * 256 + j * 64 + lane];
            dot[e] += xc.x * wc.x + xc.y * wc.y + xc.z * wc.z + xc.w * wc.w;
        }
    }
#pragma unroll
    for (int e = 0; e < NE; e++) {
        float v = dot[e];
        for (int m = 1; m < 64; m <<= 1) v += __shfl_xor(v, m, 64);
        dot[e] = v;
    }
    if (lane == 0) {
        float v1 = -1e30f, v2 = -1e30f; int i1 = 0, i2 = 0;
#pragma unroll
        for (int e = 0; e < NE; e++) {
            float v = dot[e];
            logits_out[(size_t)t * NE + e] = v;
            if (v > v1) { v2 = v1; i2 = i1; v1 = v; i1 = e; }
            else if (v > v2) { v2 = v; i2 = e; }
        }
        float s1 = 1.0f / (1.0f + expf(-v1));
        float s2 = 1.0f / (1.0f + expf(-v2));
        int p1 = atomicAdd(&cnt[i1], 1);
        tok_list[i1 * T_TOK + p1] = t; score_list[i1 * T_TOK + p1] = s1;
        int p2 = atomicAdd(&cnt[i2], 1);
        tok_list[i2 * T_TOK + p2] = t; score_list[i2 * T_TOK + p2] = s2;
        inv[t] = make_int2((i1 << 16) | p1, (i2 << 16) | p2);
    }
}

// -------- finalize: pad lists, prefix offsets, tile table, shared-expert list fill --------
__global__ void finalize_kernel(const int* __restrict__ cnt, int* __restrict__ offs,
                                int* __restrict__ tiletab,
                                int* __restrict__ tok_list, float* __restrict__ score_list) {
    __shared__ int s_cnt[NE], s_pad[NE];
    if (threadIdx.x == 0) {
        int o = 0, nt = 0;
        for (int e = 0; e < NE1; e++) {
            int c = (e == NE) ? T_TOK : cnt[e];
            int p = (c + 127) & ~127;
            offs[e] = o;
            for (int m = 0; m < (p >> 7); m++) tiletab[nt++] = (e << 8) | m;
            if (e < NE) { s_cnt[e] = c; s_pad[e] = p; }
            o += p;
        }
        for (; nt < MAXT; nt++) tiletab[nt] = -1;
    }
    __syncthreads();
    for (int e = 0; e < NE; e++) {
        for (int i = s_cnt[e] + (int)threadIdx.x; i < s_pad[e]; i += blockDim.x) {
            tok_list[e * T_TOK + i] = 0;
            score_list[e * T_TOK + i] = 0.0f;
        }
    }
    // shared expert (e=8): identity token list, score 1
    for (int i = threadIdx.x; i < T_TOK; i += blockDim.x) {
        tok_list[NE * T_TOK + i] = i;
        score_list[NE * T_TOK + i] = 1.0f;
    }
}

// ---------------- unified GEMM1: gathered x @ {gate,up}^T, fused score+SwiGLU ----------------
// Wide tile: 128 rows x 128 i-cols (gate+up) per block; 64 MFMA per barrier per wave.
__global__ __launch_bounds__(256, 2) void
moe_g1(const unsigned short* __restrict__ xb, const unsigned short* __restrict__ wg_t,
       const int* __restrict__ tiletab, const int* __restrict__ offs,
       const int* __restrict__ tok_list, const float* __restrict__ score_list,
       unsigned short* __restrict__ h) {
    int tt = tiletab[blockIdx.y];
    if (tt < 0) return;
    int e = tt >> 8, mt = tt & 255;
    int nt = blockIdx.x;  // 0..15, 128 intermediate cols

    __shared__ unsigned short As[128 * BK];   // 16 KB
    __shared__ unsigned short Bg[128 * BK];   // 16 KB
    __shared__ unsigned short Bu[128 * BK];   // 16 KB
    __shared__ int s_tok[128];
    __shared__ float s_sc[128];

    int tid = threadIdx.x, lane = tid & 63;
    int wid = tid >> 6, wm = wid >> 1, wn = wid & 1;

    if (tid < 128) {
        int slot = mt * 128 + tid;
        s_tok[tid] = tok_list[e * T_TOK + slot];
        s_sc[tid] = score_list[e * T_TOK + slot];
    }
    __syncthreads();

    const unsigned short* wg = wg_t + (size_t)e * (4096u * 1024u);
    int rsub = tid >> 3;                       // 0..31 staging row within issue
    int csw = (tid & 7) ^ (rsub & 7);          // XOR-swizzled source chunk
    const unsigned short* pA[4];
#pragma unroll
    for (int i = 0; i < 4; i++)
        pA[i] = xb + (size_t)s_tok[i * 32 + rsub] * HID + csw * 8;
    const unsigned short* pBg[4];
    const unsigned short* pBu[4];
#pragma unroll
    for (int i = 0; i < 4; i++) {
        pBg[i] = wg + (size_t)(nt * 128 + i * 32 + rsub) * HID + csw * 8;
        pBu[i] = wg + (size_t)(INTER + nt * 128 + i * 32 + rsub) * HID + csw * 8;
    }
    unsigned short* lA = As + tid * 8;         // + i*2048 per issue
    unsigned short* lBg = Bg + tid * 8;
    unsigned short* lBu = Bu + tid * 8;

    f32x4 accg[4][4], accu[4][4];
#pragma unroll
    for (int i = 0; i < 4; i++)
#pragma unroll
        for (int j = 0; j < 4; j++) { accg[i][j] = (f32x4)(0.0f); accu[i][j] = (f32x4)(0.0f); }

    int mrow = lane & 15, q = lane >> 4, x7 = lane & 7;
    for (int k0 = 0; k0 < HID; k0 += BK) {
#pragma unroll
        for (int i = 0; i < 4; i++) {
            async_ld16(pA[i] + k0, lA + i * 2048);
            async_ld16(pBg[i] + k0, lBg + i * 2048);
            async_ld16(pBu[i] + k0, lBu + i * 2048);
        }
        __syncthreads();
#pragma unroll
        for (int ksub = 0; ksub < 2; ksub++) {
            int ch = ((ksub * 4 + q) ^ x7) * 8;
            short8 af[4], bg[4], bu[4];
#pragma unroll
            for (int mi = 0; mi < 4; mi++)
                af[mi] = *(const short8*)(As + (wm * 64 + mi * 16 + mrow) * BK + ch);
#pragma unroll
            for (int ni = 0; ni < 4; ni++) {
                bg[ni] = *(const short8*)(Bg + (wn * 64 + ni * 16 + mrow) * BK + ch);
                bu[ni] = *(const short8*)(Bu + (wn * 64 + ni * 16 + mrow) * BK + ch);
            }
#pragma unroll
            for (int mi = 0; mi < 4; mi++)
#pragma unroll
                for (int ni = 0; ni < 4; ni++) {
                    accg[mi][ni] = __builtin_amdgcn_mfma_f32_16x16x32_bf16(af[mi], bg[ni], accg[mi][ni], 0, 0, 0);
                    accu[mi][ni] = __builtin_amdgcn_mfma_f32_16x16x32_bf16(af[mi], bu[ni], accu[mi][ni], 0, 0, 0);
                }
        }
        __syncthreads();
    }
    size_t rowbase = (size_t)offs[e] + (size_t)mt * 128;
    int ibase = nt * 128 + wn * 64;
#pragma unroll
    for (int mi = 0; mi < 4; mi++)
#pragma unroll
        for (int ni = 0; ni < 4; ni++)
#pragma unroll
            for (int r = 0; r < 4; r++) {
                int m = wm * 64 + mi * 16 + q * 4 + r;
                int i = ibase + ni * 16 + mrow;
                float s = s_sc[m];
                float g = accg[mi][ni][r] * s;
                float u = accu[mi][ni][r] * s;
                h[(rowbase + m) * INTER + i] = f2bf(u * g * sigm(g));
            }
}

// ---------------- unified GEMM2: h @ down^T -> dense r_out (no atomics) ----------------
// 2-deep counted-vmcnt pipeline: tile t+2 staged while tile t computes; tile t+1's
// 8 loads stay in flight across barriers (vmcnt(8), never 0 in steady state).
__global__ __launch_bounds__(256) void
moe_g2(const unsigned short* __restrict__ h, const unsigned short* __restrict__ wd_t,
       const int* __restrict__ tiletab, const int* __restrict__ offs,
       unsigned short* __restrict__ r_out) {
    int tt = tiletab[blockIdx.y];
    if (tt < 0) return;
    int e = tt >> 8, mt = tt & 255;
    int nt = blockIdx.x;  // 0..7, 128 H-cols

    __shared__ unsigned short As[2][128 * BK];   // 2 x 16 KB
    __shared__ unsigned short Bs[2][128 * BK];   // 2 x 16 KB

    int tid = threadIdx.x, lane = tid & 63;
    int wid = tid >> 6, wm = wid >> 1, wn = wid & 1;
    size_t rowbase = (size_t)offs[e] + (size_t)mt * 128;

    const unsigned short* wd = wd_t + (size_t)e * (1024u * 2048u);
    int rsub = tid >> 3;
    int csw = (tid & 7) ^ (rsub & 7);
    const unsigned short* pA[4];
    const unsigned short* pB[4];
#pragma unroll
    for (int i = 0; i < 4; i++) {
        pA[i] = h + (rowbase + i * 32 + rsub) * INTER + csw * 8;
        pB[i] = wd + (size_t)(nt * 128 + i * 32 + rsub) * INTER + csw * 8;
    }
    unsigned short* A0 = &As[0][tid * 8];
    unsigned short* A1 = &As[1][tid * 8];
    unsigned short* B0 = &Bs[0][tid * 8];
    unsigned short* B1 = &Bs[1][tid * 8];

    f32x4 acc[4][4];
#pragma unroll
    for (int i = 0; i < 4; i++)
#pragma unroll
        for (int j = 0; j < 4; j++) acc[i][j] = (f32x4)(0.0f);

    int mrow = lane & 15, q = lane >> 4, x7 = lane & 7;

    auto stage = [&](unsigned short* dA, unsigned short* dB, int k0) {
#pragma unroll
        for (int i = 0; i < 4; i++) {
            async_ld16(pA[i] + k0, dA + i * 2048);
            async_ld16(pB[i] + k0, dB + i * 2048);
        }
    };
    auto compute = [&](const unsigned short* AS, const unsigned short* BS) {
#pragma unroll
        for (int ksub = 0; ksub < 2; ksub++) {
            int ch = ((ksub * 4 + q) ^ x7) * 8;
            short8 af[4], bf_[4];
#pragma unroll
            for (int mi = 0; mi < 4; mi++)
                af[mi] = *(const short8*)(AS + (wm * 64 + mi * 16 + mrow) * BK + ch);
#pragma unroll
            for (int ni = 0; ni < 4; ni++)
                bf_[ni] = *(const short8*)(BS + (wn * 64 + ni * 16 + mrow) * BK + ch);
#pragma unroll
            for (int mi = 0; mi < 4; mi++)
#pragma unroll
                for (int ni = 0; ni < 4; ni++)
                    acc[mi][ni] = __builtin_amdgcn_mfma_f32_16x16x32_bf16(af[mi], bf_[ni], acc[mi][ni], 0, 0, 0);
        }
    };

    const int NT2 = INTER / BK;   // 32 (even)
    stage(A0, B0, 0);
    stage(A1, B1, BK);
    asm volatile("s_waitcnt vmcnt(8)" ::: "memory");
    __builtin_amdgcn_s_barrier();

    for (int t = 0; t < NT2; t += 2) {
        // ---- half A: buffer 0 ----
        compute(&As[0][0], &Bs[0][0]);
        asm volatile("s_waitcnt lgkmcnt(0)" ::: "memory");
        __builtin_amdgcn_s_barrier();
        if (t + 2 < NT2) {
            stage(A0, B0, (t + 2) * BK);
            asm volatile("s_waitcnt vmcnt(8)" ::: "memory");
        } else {
            asm volatile("s_waitcnt vmcnt(0)" ::: "memory");
        }
        __builtin_amdgcn_s_barrier();
        // ---- half B: buffer 1 ----
        compute(&As[1][0], &Bs[1][0]);
        asm volatile("s_waitcnt lgkmcnt(0)" ::: "memory");
        __builtin_amdgcn_s_barrier();
        if (t + 3 < NT2) {
            stage(A1, B1, (t + 3) * BK);
            asm volatile("s_waitcnt vmcnt(8)" ::: "memory");
        } else {
            asm volatile("s_waitcnt vmcnt(0)" ::: "memory");
        }
        __builtin_amdgcn_s_barrier();
    }

#pragma unroll
    for (int mi = 0; mi < 4; mi++)
#pragma unroll
        for (int ni = 0; ni < 4; ni++)
#pragma unroll
            for (int r = 0; r < 4; r++) {
                int m = wm * 64 + mi * 16 + (lane >> 4) * 4 + r;
                int n = nt * 128 + wn * 64 + ni * 16 + (lane & 15);
                r_out[(rowbase + m) * HID + n] = f2bf(acc[mi][ni][r]);
            }
}

// ---------------- combine: out[t] = shared + two routed contributions ----------------
__global__ void combine_kernel(const unsigned short* __restrict__ r_out,
                               const int2* __restrict__ inv, const int* __restrict__ offs,
                               float* __restrict__ out) {
    int t = blockIdx.x, tid = threadIdx.x;
    int2 iv = inv[t];
    size_t r1 = (size_t)(offs[iv.x >> 16] + (iv.x & 0xffff)) * HID;
    size_t r2 = (size_t)(offs[iv.y >> 16] + (iv.y & 0xffff)) * HID;
    size_t rs = (size_t)(offs[NE] + t) * HID;
    int i = tid * 4;
    ushort4 a = *(const ushort4*)(r_out + r1 + i);
    ushort4 b = *(const ushort4*)(r_out + r2 + i);
    ushort4 c = *(const ushort4*)(r_out + rs + i);
    float4 o;
    o.x = bf2f(a.x) + bf2f(b.x) + bf2f(c.x);
    o.y = bf2f(a.y) + bf2f(b.y) + bf2f(c.y);
    o.z = bf2f(a.z) + bf2f(b.z) + bf2f(c.z);
    o.w = bf2f(a.w) + bf2f(b.w) + bf2f(c.w);
    *(float4*)(out + (size_t)t * HID + i) = o;
}

extern "C" void kernel_launch(void* const* d_in, const int* in_sizes, int n_in,
                              void* d_out, int out_size, void* d_ws, size_t ws_size,
                              hipStream_t stream) {
    const float* x   = (const float*)d_in[0];
    const float* rw  = (const float*)d_in[1];
    const float* gup = (const float*)d_in[2];
    const float* dwn = (const float*)d_in[3];
    const float* sgw = (const float*)d_in[4];
    const float* suw = (const float*)d_in[5];
    const float* sdw = (const float*)d_in[6];
    float* out = (float*)d_out;
    float* logits = out + (size_t)T_TOK * HID;

    char* ws = (char*)d_ws;
    int*   cnt        = (int*)(ws + 0);
    int*   offs       = (int*)(ws + 64);
    int*   tiletab    = (int*)(ws + 128);                   // 104 ints
    int2*  inv        = (int2*)(ws + 4096);                 // 32 KB
    int*   tok_list   = (int*)(ws + 65536);                 // 144 KB
    float* score_list = (float*)(ws + 212992);              // 144 KB
    unsigned short* xb      = (unsigned short*)(ws + 524288);        // 8 MB
    unsigned short* w_gup_t = (unsigned short*)(ws + 9437184);       // 72 MB
    unsigned short* w_dwn_t = (unsigned short*)(ws + 89128960);      // 36 MB
    unsigned short* h       = (unsigned short*)(ws + 134217728);     // 52 MB
    unsigned short* r_out   = (unsigned short*)(ws + 201326592);     // 26 MB

    hipMemsetAsync(cnt, 0, NE * sizeof(int), stream);

    // weight prep: transpose routed weights to bf16 [N][K]; shared already [N][K]
    {
        dim3 g(4096 / 64, 1024 / 128, NE);
        transpose_cast<<<g, 256, 0, stream>>>(gup, w_gup_t, 1024, 4096,
                                              (size_t)1024 * 4096, (size_t)4096 * 1024);
    }
    {
        dim3 g(1024 / 64, 2048 / 128, NE);
        transpose_cast<<<g, 256, 0, stream>>>(dwn, w_dwn_t, 2048, 1024,
                                              (size_t)2048 * 1024, (size_t)1024 * 2048);
    }
    unsigned short* wg8 = w_gup_t + (size_t)NE * 4096 * 1024;
    {
        // three 2M-float shared weights, one fused cast launch
        int n4each = 2048 * 1024 / 4;    // 524288, multiple of 256
        cast3_kernel<<<(3 * n4each) / 256, 256, 0, stream>>>(
            sgw, suw, sdw, wg8, wg8 + 2048 * 1024,
            w_dwn_t + (size_t)NE * 1024 * 2048, n4each);
    }

    router_kernel<<<T_TOK / 4, 256, 0, stream>>>(x, rw, logits, cnt, tok_list, score_list, inv, xb);
    finalize_kernel<<<1, 128, 0, stream>>>(cnt, offs, tiletab, tok_list, score_list);

    dim3 g1(INTER / 128, MAXT);
    moe_g1<<<g1, 256, 0, stream>>>(xb, w_gup_t, tiletab, offs, tok_list, score_list, h);
    dim3 g2(HID / 128, MAXT);
    moe_g2<<<g2, 256, 0, stream>>>(h, w_dwn_t, tiletab, offs, r_out);
    combine_kernel<<<T_TOK, 256, 0, stream>>>(r_out, inv, offs, out);
}

// Round 4
// 517.664 us; speedup vs baseline: 1.2533x; 1.1677x over previous
//
#include <hip/hip_runtime.h>
#include <hip/hip_bf16.h>

#define T_TOK 4096
#define HID   1024
#define INTER 2048
#define NE    8
#define NE1   9      // 8 routed + 1 shared expert
#define BK    64     // K-tile (bf16 elems); XOR-swizzled chunks, global_load_lds staged
#define MAXT  104    // max 128-row m-tiles: <=71 routed (8192/128+7) + 32 shared
#define CNTS  16     // cnt stride in ints: one counter per 64-B cache line (atomic spread)

typedef __attribute__((ext_vector_type(8))) short short8;
typedef __attribute__((ext_vector_type(8))) unsigned short ushort8v;
typedef __attribute__((ext_vector_type(4))) float f32x4;

__device__ __forceinline__ unsigned short f2bf(float f) {
    __hip_bfloat16 h = __float2bfloat16(f);
    return __builtin_bit_cast(unsigned short, h);
}
__device__ __forceinline__ float bf2f(unsigned short u) {
    unsigned int v = ((unsigned int)u) << 16;
    return __builtin_bit_cast(float, v);
}
__device__ __forceinline__ float sigm(float x) { return 1.0f / (1.0f + __expf(-x)); }

// async global->LDS, 16B per lane. LDS dest = wave-uniform base + lane*16.
__device__ __forceinline__ void async_ld16(const void* g, void* l) {
    __builtin_amdgcn_global_load_lds(
        (const __attribute__((address_space(1))) unsigned int*)g,
        (__attribute__((address_space(3))) unsigned int*)l, 16, 0, 0);
}

// ---------------- fused fp32 -> bf16 cast for the 3 shared-expert weights ----------------
__global__ void cast3_kernel(const float* __restrict__ a, const float* __restrict__ b,
                             const float* __restrict__ c,
                             unsigned short* __restrict__ da, unsigned short* __restrict__ db,
                             unsigned short* __restrict__ dc, int n4each) {
    int i = blockIdx.x * blockDim.x + threadIdx.x;
    int region = i / n4each;              // uniform per block (n4each % 256 == 0)
    int local = i - region * n4each;
    const float* src = (region == 0) ? a : (region == 1) ? b : c;
    unsigned short* dst = (region == 0) ? da : (region == 1) ? db : dc;
    float4 v = ((const float4*)src)[local];
    ushort4 o;
    o.x = f2bf(v.x); o.y = f2bf(v.y); o.z = f2bf(v.z); o.w = f2bf(v.w);
    ((ushort4*)dst)[local] = o;
}

// ---------- fp32 [K][N] -> bf16 [N][K] transpose+cast, 128k x 64n tiles ----------
__global__ __launch_bounds__(256) void
transpose_cast(const float* __restrict__ W, unsigned short* __restrict__ Wt,
               int K, int N, size_t in_stride_e, size_t out_stride_e) {
    __shared__ float tile[128][65];
    const float* Wb = W + (size_t)blockIdx.z * in_stride_e;
    unsigned short* Wo = Wt + (size_t)blockIdx.z * out_stride_e;
    int n0 = blockIdx.x * 64, k0 = blockIdx.y * 128;
    int tid = threadIdx.x;
    int r = tid >> 4, c = tid & 15;
#pragma unroll
    for (int i = 0; i < 8; i++) {              // read: 128 k-rows x 64 n (256B segs)
        int k = i * 16 + r;
        float4 v = *(const float4*)(Wb + (size_t)(k0 + k) * N + n0 + c * 4);
        tile[k][c * 4 + 0] = v.x; tile[k][c * 4 + 1] = v.y;
        tile[k][c * 4 + 2] = v.z; tile[k][c * 4 + 3] = v.w;
    }
    __syncthreads();
#pragma unroll
    for (int i = 0; i < 4; i++) {              // write: 64 n-rows x 128 k (256B segs)
        int n = i * 16 + r;
        ushort8v o;
#pragma unroll
        for (int j = 0; j < 8; j++) o[j] = f2bf(tile[c * 8 + j][n]);
        *(ushort8v*)(Wo + (size_t)(n0 + n) * K + k0 + c * 8) = o;
    }
}

// ------- router: logits + top2 + scatter + inverse map + fused x->bf16 cast -------
__global__ void router_kernel(const float* __restrict__ x, const float* __restrict__ rw,
                              float* __restrict__ logits_out,
                              int* __restrict__ cnt, int* __restrict__ tok_list,
                              float* __restrict__ score_list, int2* __restrict__ inv,
                              unsigned short* __restrict__ xb) {
    int wave = threadIdx.x >> 6;
    int lane = threadIdx.x & 63;
    int t = blockIdx.x * 4 + wave;

    float dot[NE];
#pragma unroll
    for (int e = 0; e < NE; e++) dot[e] = 0.0f;
    const float4* xv = (const float4*)(x + (size_t)t * HID);
    ushort4* xo = (ushort4*)(xb + (size_t)t * HID);
    const float4* wv = (const float4*)rw;
#pragma unroll
    for (int j = 0; j < 4; j++) {
        float4 xc = xv[j * 64 + lane];
        ushort4 o;
        o.x = f2bf(xc.x); o.y = f2bf(xc.y); o.z = f2bf(xc.z); o.w = f2bf(xc.w);
        xo[j * 64 + lane] = o;                 // fused bf16 cast of x
#pragma unroll
        for (int e = 0; e < NE; e++) {
            float4 wc = wv[e * 256 + j * 64 + lane];
            dot[e] += xc.x * wc.x + xc.y * wc.y + xc.z * wc.z + xc.w * wc.w;
        }
    }
#pragma unroll
    for (int e = 0; e < NE; e++) {
        float v = dot[e];
        for (int m = 1; m < 64; m <<= 1) v += __shfl_xor(v, m, 64);
        dot[e] = v;
    }
    if (lane == 0) {
        float v1 = -1e30f, v2 = -1e30f; int i1 = 0, i2 = 0;
#pragma unroll
        for (int e = 0; e < NE; e++) {
            float v = dot[e];
            logits_out[(size_t)t * NE + e] = v;
            if (v > v1) { v2 = v1; i2 = i1; v1 = v; i1 = e; }
            else if (v > v2) { v2 = v; i2 = e; }
        }
        float s1 = 1.0f / (1.0f + expf(-v1));
        float s2 = 1.0f / (1.0f + expf(-v2));
        int p1 = atomicAdd(&cnt[i1 * CNTS], 1);   // one counter per cache line
        tok_list[i1 * T_TOK + p1] = t; score_list[i1 * T_TOK + p1] = s1;
        int p2 = atomicAdd(&cnt[i2 * CNTS], 1);
        tok_list[i2 * T_TOK + p2] = t; score_list[i2 * T_TOK + p2] = s2;
        inv[t] = make_int2((i1 << 16) | p1, (i2 << 16) | p2);
    }
}

// -------- finalize: pad lists, prefix offsets, tile table, shared-expert list fill --------
__global__ void finalize_kernel(const int* __restrict__ cnt, int* __restrict__ offs,
                                int* __restrict__ tiletab,
                                int* __restrict__ tok_list, float* __restrict__ score_list) {
    __shared__ int s_cnt[NE], s_pad[NE];
    if (threadIdx.x == 0) {
        int o = 0, nt = 0;
        for (int e = 0; e < NE1; e++) {
            int c = (e == NE) ? T_TOK : cnt[e * CNTS];
            int p = (c + 127) & ~127;
            offs[e] = o;
            for (int m = 0; m < (p >> 7); m++) tiletab[nt++] = (e << 8) | m;
            if (e < NE) { s_cnt[e] = c; s_pad[e] = p; }
            o += p;
        }
        for (; nt < MAXT; nt++) tiletab[nt] = -1;
    }
    __syncthreads();
    for (int e = 0; e < NE; e++) {
        for (int i = s_cnt[e] + (int)threadIdx.x; i < s_pad[e]; i += blockDim.x) {
            tok_list[e * T_TOK + i] = 0;
            score_list[e * T_TOK + i] = 0.0f;
        }
    }
    // shared expert (e=8): identity token list, score 1
    for (int i = threadIdx.x; i < T_TOK; i += blockDim.x) {
        tok_list[NE * T_TOK + i] = i;
        score_list[NE * T_TOK + i] = 1.0f;
    }
}

// ---------------- unified GEMM1: gathered x @ {gate,up}^T, fused score+SwiGLU ----------------
// Wide tile: 128 rows x 128 i-cols (gate+up) per block; 64 MFMA per barrier per wave.
__global__ __launch_bounds__(256, 2) void
moe_g1(const unsigned short* __restrict__ xb, const unsigned short* __restrict__ wg_t,
       const int* __restrict__ tiletab, const int* __restrict__ offs,
       const int* __restrict__ tok_list, const float* __restrict__ score_list,
       unsigned short* __restrict__ h) {
    int tt = tiletab[blockIdx.y];
    if (tt < 0) return;
    int e = tt >> 8, mt = tt & 255;
    int nt = blockIdx.x;  // 0..15, 128 intermediate cols

    __shared__ unsigned short As[128 * BK];   // 16 KB
    __shared__ unsigned short Bg[128 * BK];   // 16 KB
    __shared__ unsigned short Bu[128 * BK];   // 16 KB
    __shared__ int s_tok[128];
    __shared__ float s_sc[128];

    int tid = threadIdx.x, lane = tid & 63;
    int wid = tid >> 6, wm = wid >> 1, wn = wid & 1;

    if (tid < 128) {
        int slot = mt * 128 + tid;
        s_tok[tid] = tok_list[e * T_TOK + slot];
        s_sc[tid] = score_list[e * T_TOK + slot];
    }
    __syncthreads();

    const unsigned short* wg = wg_t + (size_t)e * (4096u * 1024u);
    int rsub = tid >> 3;                       // 0..31 staging row within issue
    int csw = (tid & 7) ^ (rsub & 7);          // XOR-swizzled source chunk
    const unsigned short* pA[4];
#pragma unroll
    for (int i = 0; i < 4; i++)
        pA[i] = xb + (size_t)s_tok[i * 32 + rsub] * HID + csw * 8;
    const unsigned short* pBg[4];
    const unsigned short* pBu[4];
#pragma unroll
    for (int i = 0; i < 4; i++) {
        pBg[i] = wg + (size_t)(nt * 128 + i * 32 + rsub) * HID + csw * 8;
        pBu[i] = wg + (size_t)(INTER + nt * 128 + i * 32 + rsub) * HID + csw * 8;
    }
    unsigned short* lA = As + tid * 8;         // + i*2048 per issue
    unsigned short* lBg = Bg + tid * 8;
    unsigned short* lBu = Bu + tid * 8;

    f32x4 accg[4][4], accu[4][4];
#pragma unroll
    for (int i = 0; i < 4; i++)
#pragma unroll
        for (int j = 0; j < 4; j++) { accg[i][j] = (f32x4)(0.0f); accu[i][j] = (f32x4)(0.0f); }

    int mrow = lane & 15, q = lane >> 4, x7 = lane & 7;
    for (int k0 = 0; k0 < HID; k0 += BK) {
#pragma unroll
        for (int i = 0; i < 4; i++) {
            async_ld16(pA[i] + k0, lA + i * 2048);
            async_ld16(pBg[i] + k0, lBg + i * 2048);
            async_ld16(pBu[i] + k0, lBu + i * 2048);
        }
        __syncthreads();
#pragma unroll
        for (int ksub = 0; ksub < 2; ksub++) {
            int ch = ((ksub * 4 + q) ^ x7) * 8;
            short8 af[4], bg[4], bu[4];
#pragma unroll
            for (int mi = 0; mi < 4; mi++)
                af[mi] = *(const short8*)(As + (wm * 64 + mi * 16 + mrow) * BK + ch);
#pragma unroll
            for (int ni = 0; ni < 4; ni++) {
                bg[ni] = *(const short8*)(Bg + (wn * 64 + ni * 16 + mrow) * BK + ch);
                bu[ni] = *(const short8*)(Bu + (wn * 64 + ni * 16 + mrow) * BK + ch);
            }
#pragma unroll
            for (int mi = 0; mi < 4; mi++)
#pragma unroll
                for (int ni = 0; ni < 4; ni++) {
                    accg[mi][ni] = __builtin_amdgcn_mfma_f32_16x16x32_bf16(af[mi], bg[ni], accg[mi][ni], 0, 0, 0);
                    accu[mi][ni] = __builtin_amdgcn_mfma_f32_16x16x32_bf16(af[mi], bu[ni], accu[mi][ni], 0, 0, 0);
                }
        }
        __syncthreads();
    }
    size_t rowbase = (size_t)offs[e] + (size_t)mt * 128;
    int ibase = nt * 128 + wn * 64;
#pragma unroll
    for (int mi = 0; mi < 4; mi++)
#pragma unroll
        for (int ni = 0; ni < 4; ni++)
#pragma unroll
            for (int r = 0; r < 4; r++) {
                int m = wm * 64 + mi * 16 + q * 4 + r;
                int i = ibase + ni * 16 + mrow;
                float s = s_sc[m];
                float g = accg[mi][ni][r] * s;
                float u = accu[mi][ni][r] * s;
                h[(rowbase + m) * INTER + i] = f2bf(u * g * sigm(g));
            }
}

// ---------------- unified GEMM2: h @ down^T -> dense r_out (no atomics) ----------------
// Wide tile: 128 rows x 256 H-cols per block; 64 MFMA per barrier per wave.
__global__ __launch_bounds__(256, 2) void
moe_g2(const unsigned short* __restrict__ h, const unsigned short* __restrict__ wd_t,
       const int* __restrict__ tiletab, const int* __restrict__ offs,
       unsigned short* __restrict__ r_out) {
    int tt = tiletab[blockIdx.y];
    if (tt < 0) return;
    int e = tt >> 8, mt = tt & 255;
    int nt = blockIdx.x;  // 0..3, 256 H-cols

    __shared__ unsigned short As[128 * BK];   // 16 KB
    __shared__ unsigned short Bs[256 * BK];   // 32 KB

    int tid = threadIdx.x, lane = tid & 63;
    int wid = tid >> 6, wm = wid >> 1, wn = wid & 1;
    size_t rowbase = (size_t)offs[e] + (size_t)mt * 128;

    const unsigned short* wd = wd_t + (size_t)e * (1024u * 2048u);
    int rsub = tid >> 3;
    int csw = (tid & 7) ^ (rsub & 7);
    const unsigned short* pA[4];
    const unsigned short* pB[8];
#pragma unroll
    for (int i = 0; i < 4; i++)
        pA[i] = h + (rowbase + i * 32 + rsub) * INTER + csw * 8;
#pragma unroll
    for (int i = 0; i < 8; i++)
        pB[i] = wd + (size_t)(nt * 256 + i * 32 + rsub) * INTER + csw * 8;
    unsigned short* lA = As + tid * 8;
    unsigned short* lB = Bs + tid * 8;

    f32x4 acc[4][8];
#pragma unroll
    for (int i = 0; i < 4; i++)
#pragma unroll
        for (int j = 0; j < 8; j++) acc[i][j] = (f32x4)(0.0f);

    int mrow = lane & 15, q = lane >> 4, x7 = lane & 7;
    for (int k0 = 0; k0 < INTER; k0 += BK) {
#pragma unroll
        for (int i = 0; i < 4; i++) async_ld16(pA[i] + k0, lA + i * 2048);
#pragma unroll
        for (int i = 0; i < 8; i++) async_ld16(pB[i] + k0, lB + i * 2048);
        __syncthreads();
#pragma unroll
        for (int ksub = 0; ksub < 2; ksub++) {
            int ch = ((ksub * 4 + q) ^ x7) * 8;
            short8 af[4], bf_[8];
#pragma unroll
            for (int mi = 0; mi < 4; mi++)
                af[mi] = *(const short8*)(As + (wm * 64 + mi * 16 + mrow) * BK + ch);
#pragma unroll
            for (int ni = 0; ni < 8; ni++)
                bf_[ni] = *(const short8*)(Bs + (wn * 128 + ni * 16 + mrow) * BK + ch);
#pragma unroll
            for (int mi = 0; mi < 4; mi++)
#pragma unroll
                for (int ni = 0; ni < 8; ni++)
                    acc[mi][ni] = __builtin_amdgcn_mfma_f32_16x16x32_bf16(af[mi], bf_[ni], acc[mi][ni], 0, 0, 0);
        }
        __syncthreads();
    }
#pragma unroll
    for (int mi = 0; mi < 4; mi++)
#pragma unroll
        for (int ni = 0; ni < 8; ni++)
#pragma unroll
            for (int r = 0; r < 4; r++) {
                int m = wm * 64 + mi * 16 + q * 4 + r;
                int n = nt * 256 + wn * 128 + ni * 16 + mrow;
                r_out[(rowbase + m) * HID + n] = f2bf(acc[mi][ni][r]);
            }
}

// ---------------- combine: out[t] = shared + two routed contributions ----------------
__global__ void combine_kernel(const unsigned short* __restrict__ r_out,
                               const int2* __restrict__ inv, const int* __restrict__ offs,
                               float* __restrict__ out) {
    int t = blockIdx.x, tid = threadIdx.x;
    int2 iv = inv[t];
    size_t r1 = (size_t)(offs[iv.x >> 16] + (iv.x & 0xffff)) * HID;
    size_t r2 = (size_t)(offs[iv.y >> 16] + (iv.y & 0xffff)) * HID;
    size_t rs = (size_t)(offs[NE] + t) * HID;
    int i = tid * 4;
    ushort4 a = *(const ushort4*)(r_out + r1 + i);
    ushort4 b = *(const ushort4*)(r_out + r2 + i);
    ushort4 c = *(const ushort4*)(r_out + rs + i);
    float4 o;
    o.x = bf2f(a.x) + bf2f(b.x) + bf2f(c.x);
    o.y = bf2f(a.y) + bf2f(b.y) + bf2f(c.y);
    o.z = bf2f(a.z) + bf2f(b.z) + bf2f(c.z);
    o.w = bf2f(a.w) + bf2f(b.w) + bf2f(c.w);
    *(float4*)(out + (size_t)t * HID + i) = o;
}

extern "C" void kernel_launch(void* const* d_in, const int* in_sizes, int n_in,
                              void* d_out, int out_size, void* d_ws, size_t ws_size,
                              hipStream_t stream) {
    const float* x   = (const float*)d_in[0];
    const float* rw  = (const float*)d_in[1];
    const float* gup = (const float*)d_in[2];
    const float* dwn = (const float*)d_in[3];
    const float* sgw = (const float*)d_in[4];
    const float* suw = (const float*)d_in[5];
    const float* sdw = (const float*)d_in[6];
    float* out = (float*)d_out;
    float* logits = out + (size_t)T_TOK * HID;

    char* ws = (char*)d_ws;
    int*   cnt        = (int*)(ws + 0);                     // NE counters, 64-B stride
    int*   offs       = (int*)(ws + 1024);
    int*   tiletab    = (int*)(ws + 1152);                  // 104 ints
    int2*  inv        = (int2*)(ws + 4096);                 // 32 KB
    int*   tok_list   = (int*)(ws + 65536);                 // 144 KB
    float* score_list = (float*)(ws + 212992);              // 144 KB
    unsigned short* xb      = (unsigned short*)(ws + 524288);        // 8 MB
    unsigned short* w_gup_t = (unsigned short*)(ws + 9437184);       // 72 MB
    unsigned short* w_dwn_t = (unsigned short*)(ws + 89128960);      // 36 MB
    unsigned short* h       = (unsigned short*)(ws + 134217728);     // 52 MB
    unsigned short* r_out   = (unsigned short*)(ws + 201326592);     // 26 MB

    hipMemsetAsync(cnt, 0, NE * CNTS * sizeof(int), stream);

    // weight prep: transpose routed weights to bf16 [N][K]; shared already [N][K]
    {
        dim3 g(4096 / 64, 1024 / 128, NE);
        transpose_cast<<<g, 256, 0, stream>>>(gup, w_gup_t, 1024, 4096,
                                              (size_t)1024 * 4096, (size_t)4096 * 1024);
    }
    {
        dim3 g(1024 / 64, 2048 / 128, NE);
        transpose_cast<<<g, 256, 0, stream>>>(dwn, w_dwn_t, 2048, 1024,
                                              (size_t)2048 * 1024, (size_t)1024 * 2048);
    }
    unsigned short* wg8 = w_gup_t + (size_t)NE * 4096 * 1024;
    {
        // three 2M-float shared weights, one fused cast launch
        int n4each = 2048 * 1024 / 4;    // 524288, multiple of 256
        cast3_kernel<<<(3 * n4each) / 256, 256, 0, stream>>>(
            sgw, suw, sdw, wg8, wg8 + 2048 * 1024,
            w_dwn_t + (size_t)NE * 1024 * 2048, n4each);
    }

    router_kernel<<<T_TOK / 4, 256, 0, stream>>>(x, rw, logits, cnt, tok_list, score_list, inv, xb);
    finalize_kernel<<<1, 128, 0, stream>>>(cnt, offs, tiletab, tok_list, score_list);

    dim3 g1(INTER / 128, MAXT);
    moe_g1<<<g1, 256, 0, stream>>>(xb, w_gup_t, tiletab, offs, tok_list, score_list, h);
    dim3 g2(HID / 256, MAXT);
    moe_g2<<<g2, 256, 0, stream>>>(h, w_dwn_t, tiletab, offs, r_out);
    combine_kernel<<<T_TOK, 256, 0, stream>>>(r_out, inv, offs, out);
}

// Round 5
// 509.294 us; speedup vs baseline: 1.2739x; 1.0164x over previous
//
#include <hip/hip_runtime.h>
#include <hip/hip_bf16.h>

#define T_TOK 4096
#define HID   1024
#define INTER 2048
#define NE    8
#define NE1   9      // 8 routed + 1 shared expert
#define BK    64     // K-tile (bf16 elems); XOR-swizzled chunks, global_load_lds staged
#define MAXT  104    // max 128-row m-tiles: <=71 routed (8192/128+7) + 32 shared
#define CNTS  16     // cnt stride in ints: one counter per 64-B cache line (atomic spread)

typedef __attribute__((ext_vector_type(8))) short short8;
typedef __attribute__((ext_vector_type(8))) unsigned short ushort8v;
typedef __attribute__((ext_vector_type(4))) float f32x4;

__device__ __forceinline__ unsigned short f2bf(float f) {
    __hip_bfloat16 h = __float2bfloat16(f);
    return __builtin_bit_cast(unsigned short, h);
}
__device__ __forceinline__ float bf2f(unsigned short u) {
    unsigned int v = ((unsigned int)u) << 16;
    return __builtin_bit_cast(float, v);
}
__device__ __forceinline__ float sigm(float x) { return 1.0f / (1.0f + __expf(-x)); }

// async global->LDS, 16B per lane. LDS dest = wave-uniform base + lane*16.
__device__ __forceinline__ void async_ld16(const void* g, void* l) {
    __builtin_amdgcn_global_load_lds(
        (const __attribute__((address_space(1))) unsigned int*)g,
        (__attribute__((address_space(3))) unsigned int*)l, 16, 0, 0);
}

// ---------------- fused fp32 -> bf16 cast for the 3 shared-expert weights ----------------
__global__ void cast3_kernel(const float* __restrict__ a, const float* __restrict__ b,
                             const float* __restrict__ c,
                             unsigned short* __restrict__ da, unsigned short* __restrict__ db,
                             unsigned short* __restrict__ dc, int n4each) {
    int i = blockIdx.x * blockDim.x + threadIdx.x;
    int region = i / n4each;              // uniform per block (n4each % 256 == 0)
    int local = i - region * n4each;
    const float* src = (region == 0) ? a : (region == 1) ? b : c;
    unsigned short* dst = (region == 0) ? da : (region == 1) ? db : dc;
    float4 v = ((const float4*)src)[local];
    ushort4 o;
    o.x = f2bf(v.x); o.y = f2bf(v.y); o.z = f2bf(v.z); o.w = f2bf(v.w);
    ((ushort4*)dst)[local] = o;
}

// ---------- fp32 [K][N] -> bf16 [N][K] transpose+cast, 128k x 128n tiles ----------
// bf16 stored in LDS (half the bytes of the old fp32 tile); pad 132 -> 2-way bank
// conflicts max on both sides (free). 256-B coalesced segments on read and write.
__global__ __launch_bounds__(256) void
transpose_cast(const float* __restrict__ W, unsigned short* __restrict__ Wt,
               int K, int N, size_t in_stride_e, size_t out_stride_e) {
    __shared__ unsigned short tile[128][132];   // 33.8 KB
    const float* Wb = W + (size_t)blockIdx.z * in_stride_e;
    unsigned short* Wo = Wt + (size_t)blockIdx.z * out_stride_e;
    int n0 = blockIdx.x * 128, k0 = blockIdx.y * 128;
    int tid = threadIdx.x;
    int rr = tid >> 5, cc = tid & 31;          // 8 k-rows x 32 float4 per pass
#pragma unroll
    for (int i = 0; i < 16; i++) {             // read: 128 k-rows x 128 n
        int k = i * 8 + rr;
        float4 v = *(const float4*)(Wb + (size_t)(k0 + k) * N + n0 + cc * 4);
        tile[k][cc * 4 + 0] = f2bf(v.x);
        tile[k][cc * 4 + 1] = f2bf(v.y);
        tile[k][cc * 4 + 2] = f2bf(v.z);
        tile[k][cc * 4 + 3] = f2bf(v.w);
    }
    __syncthreads();
    int r2 = tid >> 4, c2 = tid & 15;          // 16 n-rows x 16 ushort8 per pass
#pragma unroll
    for (int i = 0; i < 8; i++) {              // write: 128 n-rows x 128 k
        int n = i * 16 + r2;
        ushort8v o;
#pragma unroll
        for (int j = 0; j < 8; j++) o[j] = tile[c2 * 8 + j][n];
        *(ushort8v*)(Wo + (size_t)(n0 + n) * K + k0 + c2 * 8) = o;
    }
}

// ------- router: logits + top2 + scatter + inverse map + fused x->bf16 cast -------
__global__ void router_kernel(const float* __restrict__ x, const float* __restrict__ rw,
                              float* __restrict__ logits_out,
                              int* __restrict__ cnt, int* __restrict__ tok_list,
                              float* __restrict__ score_list, int2* __restrict__ inv,
                              unsigned short* __restrict__ xb) {
    int wave = threadIdx.x >> 6;
    int lane = threadIdx.x & 63;
    int t = blockIdx.x * 4 + wave;

    float dot[NE];
#pragma unroll
    for (int e = 0; e < NE; e++) dot[e] = 0.0f;
    const float4* xv = (const float4*)(x + (size_t)t * HID);
    ushort4* xo = (ushort4*)(xb + (size_t)t * HID);
    const float4* wv = (const float4*)rw;
#pragma unroll
    for (int j = 0; j < 4; j++) {
        float4 xc = xv[j * 64 + lane];
        ushort4 o;
        o.x = f2bf(xc.x); o.y = f2bf(xc.y); o.z = f2bf(xc.z); o.w = f2bf(xc.w);
        xo[j * 64 + lane] = o;                 // fused bf16 cast of x
#pragma unroll
        for (int e = 0; e < NE; e++) {
            float4 wc = wv[e * 256 + j * 64 + lane];
            dot[e] += xc.x * wc.x + xc.y * wc.y + xc.z * wc.z + xc.w * wc.w;
        }
    }
#pragma unroll
    for (int e = 0; e < NE; e++) {
        float v = dot[e];
        for (int m = 1; m < 64; m <<= 1) v += __shfl_xor(v, m, 64);
        dot[e] = v;
    }
    if (lane == 0) {
        float v1 = -1e30f, v2 = -1e30f; int i1 = 0, i2 = 0;
#pragma unroll
        for (int e = 0; e < NE; e++) {
            float v = dot[e];
            logits_out[(size_t)t * NE + e] = v;
            if (v > v1) { v2 = v1; i2 = i1; v1 = v; i1 = e; }
            else if (v > v2) { v2 = v; i2 = e; }
        }
        float s1 = 1.0f / (1.0f + expf(-v1));
        float s2 = 1.0f / (1.0f + expf(-v2));
        int p1 = atomicAdd(&cnt[i1 * CNTS], 1);   // one counter per cache line
        tok_list[i1 * T_TOK + p1] = t; score_list[i1 * T_TOK + p1] = s1;
        int p2 = atomicAdd(&cnt[i2 * CNTS], 1);
        tok_list[i2 * T_TOK + p2] = t; score_list[i2 * T_TOK + p2] = s2;
        inv[t] = make_int2((i1 << 16) | p1, (i2 << 16) | p2);
    }
}

// -------- finalize: prefix on thread0 only; tiletab/pad/shared fills parallel --------
__global__ void finalize_kernel(const int* __restrict__ cnt, int* __restrict__ offs,
                                int* __restrict__ tiletab,
                                int* __restrict__ tok_list, float* __restrict__ score_list) {
    __shared__ int s_cnt[NE], s_pad[NE];
    __shared__ int s_base[NE1 + 1];   // tile-index prefix per expert
    if (threadIdx.x == 0) {
        int o = 0, nt = 0;
        for (int e = 0; e < NE1; e++) {
            int c = (e == NE) ? T_TOK : cnt[e * CNTS];
            int p = (c + 127) & ~127;
            offs[e] = o;
            s_base[e] = nt;
            nt += p >> 7;
            if (e < NE) { s_cnt[e] = c; s_pad[e] = p; }
            o += p;
        }
        s_base[NE1] = nt;
    }
    __syncthreads();
    int ntot = s_base[NE1];
    for (int idx = threadIdx.x; idx < MAXT; idx += blockDim.x) {
        int v = -1;
        if (idx < ntot) {
            int e = 0;
            while (idx >= s_base[e + 1]) e++;
            v = (e << 8) | (idx - s_base[e]);
        }
        tiletab[idx] = v;
    }
    for (int e = 0; e < NE; e++) {
        for (int i = s_cnt[e] + (int)threadIdx.x; i < s_pad[e]; i += blockDim.x) {
            tok_list[e * T_TOK + i] = 0;
            score_list[e * T_TOK + i] = 0.0f;
        }
    }
    // shared expert (e=8): identity token list, score 1
    for (int i = threadIdx.x; i < T_TOK; i += blockDim.x) {
        tok_list[NE * T_TOK + i] = i;
        score_list[NE * T_TOK + i] = 1.0f;
    }
}

// ---------------- unified GEMM1: gathered x @ {gate,up}^T, fused score+SwiGLU ----------------
// Wide tile: 128 rows x 128 i-cols (gate+up) per block; 64 MFMA per barrier per wave.
__global__ __launch_bounds__(256, 2) void
moe_g1(const unsigned short* __restrict__ xb, const unsigned short* __restrict__ wg_t,
       const int* __restrict__ tiletab, const int* __restrict__ offs,
       const int* __restrict__ tok_list, const float* __restrict__ score_list,
       unsigned short* __restrict__ h) {
    int tt = tiletab[blockIdx.y];
    if (tt < 0) return;
    int e = tt >> 8, mt = tt & 255;
    int nt = blockIdx.x;  // 0..15, 128 intermediate cols

    __shared__ unsigned short As[128 * BK];   // 16 KB
    __shared__ unsigned short Bg[128 * BK];   // 16 KB
    __shared__ unsigned short Bu[128 * BK];   // 16 KB
    __shared__ int s_tok[128];
    __shared__ float s_sc[128];

    int tid = threadIdx.x, lane = tid & 63;
    int wid = tid >> 6, wm = wid >> 1, wn = wid & 1;

    if (tid < 128) {
        int slot = mt * 128 + tid;
        s_tok[tid] = tok_list[e * T_TOK + slot];
        s_sc[tid] = score_list[e * T_TOK + slot];
    }
    __syncthreads();

    const unsigned short* wg = wg_t + (size_t)e * (4096u * 1024u);
    int rsub = tid >> 3;                       // 0..31 staging row within issue
    int csw = (tid & 7) ^ (rsub & 7);          // XOR-swizzled source chunk
    const unsigned short* pA[4];
#pragma unroll
    for (int i = 0; i < 4; i++)
        pA[i] = xb + (size_t)s_tok[i * 32 + rsub] * HID + csw * 8;
    const unsigned short* pBg[4];
    const unsigned short* pBu[4];
#pragma unroll
    for (int i = 0; i < 4; i++) {
        pBg[i] = wg + (size_t)(nt * 128 + i * 32 + rsub) * HID + csw * 8;
        pBu[i] = wg + (size_t)(INTER + nt * 128 + i * 32 + rsub) * HID + csw * 8;
    }
    unsigned short* lA = As + tid * 8;         // + i*2048 per issue
    unsigned short* lBg = Bg + tid * 8;
    unsigned short* lBu = Bu + tid * 8;

    f32x4 accg[4][4], accu[4][4];
#pragma unroll
    for (int i = 0; i < 4; i++)
#pragma unroll
        for (int j = 0; j < 4; j++) { accg[i][j] = (f32x4)(0.0f); accu[i][j] = (f32x4)(0.0f); }

    int mrow = lane & 15, q = lane >> 4, x7 = lane & 7;
    for (int k0 = 0; k0 < HID; k0 += BK) {
#pragma unroll
        for (int i = 0; i < 4; i++) {
            async_ld16(pA[i] + k0, lA + i * 2048);
            async_ld16(pBg[i] + k0, lBg + i * 2048);
            async_ld16(pBu[i] + k0, lBu + i * 2048);
        }
        __syncthreads();
#pragma unroll
        for (int ksub = 0; ksub < 2; ksub++) {
            int ch = ((ksub * 4 + q) ^ x7) * 8;
            short8 af[4], bg[4], bu[4];
#pragma unroll
            for (int mi = 0; mi < 4; mi++)
                af[mi] = *(const short8*)(As + (wm * 64 + mi * 16 + mrow) * BK + ch);
#pragma unroll
            for (int ni = 0; ni < 4; ni++) {
                bg[ni] = *(const short8*)(Bg + (wn * 64 + ni * 16 + mrow) * BK + ch);
                bu[ni] = *(const short8*)(Bu + (wn * 64 + ni * 16 + mrow) * BK + ch);
            }
#pragma unroll
            for (int mi = 0; mi < 4; mi++)
#pragma unroll
                for (int ni = 0; ni < 4; ni++) {
                    accg[mi][ni] = __builtin_amdgcn_mfma_f32_16x16x32_bf16(af[mi], bg[ni], accg[mi][ni], 0, 0, 0);
                    accu[mi][ni] = __builtin_amdgcn_mfma_f32_16x16x32_bf16(af[mi], bu[ni], accu[mi][ni], 0, 0, 0);
                }
        }
        __syncthreads();
    }
    size_t rowbase = (size_t)offs[e] + (size_t)mt * 128;
    int ibase = nt * 128 + wn * 64;
#pragma unroll
    for (int mi = 0; mi < 4; mi++)
#pragma unroll
        for (int ni = 0; ni < 4; ni++)
#pragma unroll
            for (int r = 0; r < 4; r++) {
                int m = wm * 64 + mi * 16 + q * 4 + r;
                int i = ibase + ni * 16 + mrow;
                float s = s_sc[m];
                float g = accg[mi][ni][r] * s;
                float u = accu[mi][ni][r] * s;
                h[(rowbase + m) * INTER + i] = f2bf(u * g * sigm(g));
            }
}

// ---------------- unified GEMM2: h @ down^T -> dense r_out (no atomics) ----------------
// Wide tile: 128 rows x 256 H-cols per block; 64 MFMA per barrier per wave.
__global__ __launch_bounds__(256, 2) void
moe_g2(const unsigned short* __restrict__ h, const unsigned short* __restrict__ wd_t,
       const int* __restrict__ tiletab, const int* __restrict__ offs,
       unsigned short* __restrict__ r_out) {
    int tt = tiletab[blockIdx.y];
    if (tt < 0) return;
    int e = tt >> 8, mt = tt & 255;
    int nt = blockIdx.x;  // 0..3, 256 H-cols

    __shared__ unsigned short As[128 * BK];   // 16 KB
    __shared__ unsigned short Bs[256 * BK];   // 32 KB

    int tid = threadIdx.x, lane = tid & 63;
    int wid = tid >> 6, wm = wid >> 1, wn = wid & 1;
    size_t rowbase = (size_t)offs[e] + (size_t)mt * 128;

    const unsigned short* wd = wd_t + (size_t)e * (1024u * 2048u);
    int rsub = tid >> 3;
    int csw = (tid & 7) ^ (rsub & 7);
    const unsigned short* pA[4];
    const unsigned short* pB[8];
#pragma unroll
    for (int i = 0; i < 4; i++)
        pA[i] = h + (rowbase + i * 32 + rsub) * INTER + csw * 8;
#pragma unroll
    for (int i = 0; i < 8; i++)
        pB[i] = wd + (size_t)(nt * 256 + i * 32 + rsub) * INTER + csw * 8;
    unsigned short* lA = As + tid * 8;
    unsigned short* lB = Bs + tid * 8;

    f32x4 acc[4][8];
#pragma unroll
    for (int i = 0; i < 4; i++)
#pragma unroll
        for (int j = 0; j < 8; j++) acc[i][j] = (f32x4)(0.0f);

    int mrow = lane & 15, q = lane >> 4, x7 = lane & 7;
    for (int k0 = 0; k0 < INTER; k0 += BK) {
#pragma unroll
        for (int i = 0; i < 4; i++) async_ld16(pA[i] + k0, lA + i * 2048);
#pragma unroll
        for (int i = 0; i < 8; i++) async_ld16(pB[i] + k0, lB + i * 2048);
        __syncthreads();
#pragma unroll
        for (int ksub = 0; ksub < 2; ksub++) {
            int ch = ((ksub * 4 + q) ^ x7) * 8;
            short8 af[4], bf_[8];
#pragma unroll
            for (int mi = 0; mi < 4; mi++)
                af[mi] = *(const short8*)(As + (wm * 64 + mi * 16 + mrow) * BK + ch);
#pragma unroll
            for (int ni = 0; ni < 8; ni++)
                bf_[ni] = *(const short8*)(Bs + (wn * 128 + ni * 16 + mrow) * BK + ch);
#pragma unroll
            for (int mi = 0; mi < 4; mi++)
#pragma unroll
                for (int ni = 0; ni < 8; ni++)
                    acc[mi][ni] = __builtin_amdgcn_mfma_f32_16x16x32_bf16(af[mi], bf_[ni], acc[mi][ni], 0, 0, 0);
        }
        __syncthreads();
    }
#pragma unroll
    for (int mi = 0; mi < 4; mi++)
#pragma unroll
        for (int ni = 0; ni < 8; ni++)
#pragma unroll
            for (int r = 0; r < 4; r++) {
                int m = wm * 64 + mi * 16 + q * 4 + r;
                int n = nt * 256 + wn * 128 + ni * 16 + mrow;
                r_out[(rowbase + m) * HID + n] = f2bf(acc[mi][ni][r]);
            }
}

// ---------------- combine: out[t] = shared + two routed contributions ----------------
__global__ void combine_kernel(const unsigned short* __restrict__ r_out,
                               const int2* __restrict__ inv, const int* __restrict__ offs,
                               float* __restrict__ out) {
    int t = blockIdx.x, tid = threadIdx.x;
    int2 iv = inv[t];
    size_t r1 = (size_t)(offs[iv.x >> 16] + (iv.x & 0xffff)) * HID;
    size_t r2 = (size_t)(offs[iv.y >> 16] + (iv.y & 0xffff)) * HID;
    size_t rs = (size_t)(offs[NE] + t) * HID;
    int i = tid * 4;
    ushort4 a = *(const ushort4*)(r_out + r1 + i);
    ushort4 b = *(const ushort4*)(r_out + r2 + i);
    ushort4 c = *(const ushort4*)(r_out + rs + i);
    float4 o;
    o.x = bf2f(a.x) + bf2f(b.x) + bf2f(c.x);
    o.y = bf2f(a.y) + bf2f(b.y) + bf2f(c.y);
    o.z = bf2f(a.z) + bf2f(b.z) + bf2f(c.z);
    o.w = bf2f(a.w) + bf2f(b.w) + bf2f(c.w);
    *(float4*)(out + (size_t)t * HID + i) = o;
}

extern "C" void kernel_launch(void* const* d_in, const int* in_sizes, int n_in,
                              void* d_out, int out_size, void* d_ws, size_t ws_size,
                              hipStream_t stream) {
    const float* x   = (const float*)d_in[0];
    const float* rw  = (const float*)d_in[1];
    const float* gup = (const float*)d_in[2];
    const float* dwn = (const float*)d_in[3];
    const float* sgw = (const float*)d_in[4];
    const float* suw = (const float*)d_in[5];
    const float* sdw = (const float*)d_in[6];
    float* out = (float*)d_out;
    float* logits = out + (size_t)T_TOK * HID;

    char* ws = (char*)d_ws;
    int*   cnt        = (int*)(ws + 0);                     // NE counters, 64-B stride
    int*   offs       = (int*)(ws + 1024);
    int*   tiletab    = (int*)(ws + 1152);                  // 104 ints
    int2*  inv        = (int2*)(ws + 4096);                 // 32 KB
    int*   tok_list   = (int*)(ws + 65536);                 // 144 KB
    float* score_list = (float*)(ws + 212992);              // 144 KB
    unsigned short* xb      = (unsigned short*)(ws + 524288);        // 8 MB
    unsigned short* w_gup_t = (unsigned short*)(ws + 9437184);       // 72 MB
    unsigned short* w_dwn_t = (unsigned short*)(ws + 89128960);      // 36 MB
    unsigned short* h       = (unsigned short*)(ws + 134217728);     // 52 MB
    unsigned short* r_out   = (unsigned short*)(ws + 201326592);     // 26 MB

    hipMemsetAsync(cnt, 0, NE * CNTS * sizeof(int), stream);

    // weight prep: transpose routed weights to bf16 [N][K]; shared already [N][K]
    {
        dim3 g(4096 / 128, 1024 / 128, NE);
        transpose_cast<<<g, 256, 0, stream>>>(gup, w_gup_t, 1024, 4096,
                                              (size_t)1024 * 4096, (size_t)4096 * 1024);
    }
    {
        dim3 g(1024 / 128, 2048 / 128, NE);
        transpose_cast<<<g, 256, 0, stream>>>(dwn, w_dwn_t, 2048, 1024,
                                              (size_t)2048 * 1024, (size_t)1024 * 2048);
    }
    unsigned short* wg8 = w_gup_t + (size_t)NE * 4096 * 1024;
    {
        // three 2M-float shared weights, one fused cast launch
        int n4each = 2048 * 1024 / 4;    // 524288, multiple of 256
        cast3_kernel<<<(3 * n4each) / 256, 256, 0, stream>>>(
            sgw, suw, sdw, wg8, wg8 + 2048 * 1024,
            w_dwn_t + (size_t)NE * 1024 * 2048, n4each);
    }

    router_kernel<<<T_TOK / 4, 256, 0, stream>>>(x, rw, logits, cnt, tok_list, score_list, inv, xb);
    finalize_kernel<<<1, 256, 0, stream>>>(cnt, offs, tiletab, tok_list, score_list);

    dim3 g1(INTER / 128, MAXT);
    moe_g1<<<g1, 256, 0, stream>>>(xb, w_gup_t, tiletab, offs, tok_list, score_list, h);
    dim3 g2(HID / 256, MAXT);
    moe_g2<<<g2, 256, 0, stream>>>(h, w_dwn_t, tiletab, offs, r_out);
    combine_kernel<<<T_TOK, 256, 0, stream>>>(r_out, inv, offs, out);
}